// Round 4
// baseline (341.925 us; speedup 1.0000x reference)
//
#include <hip/hip_runtime.h>
#include <hip/hip_bf16.h>
#include <math.h>

#define NN 8
#define CH 128
#define HH 36
#define WWI 36
#define PP 1296      // 36*36
#define DD 1156      // 34*34
#define VP 1280      // vb row pitch (shorts) — covers d-tail reads to 1279
#define KC 1152      // 128*9

typedef __attribute__((ext_vector_type(8))) short short8;
typedef __attribute__((ext_vector_type(4))) float f32x4;

__device__ inline unsigned short f2bf(float f) {
    __hip_bfloat16 h = __float2bfloat16(f);
    return __builtin_bit_cast(unsigned short, h);
}
__device__ inline float fast_tanh(float x) {
    float e = __expf(2.f * x);
    return 1.f - 2.f / (e + 1.f);
}
#define MFMA(a, b, c) __builtin_amdgcn_mfma_f32_16x16x32_bf16((a), (b), (c), 0, 0, 0)

// ---------------------------------------------------------------------------
// hconst[co] = b_h[co] + sum_ci w_h[co,256+ci] * vc[ci]; vc = folded c-branch
// attention (spatially-uniform c => uniform softmax => constant v_c).
// ---------------------------------------------------------------------------
__global__ void k_const(const float* __restrict__ c0, const float* __restrict__ w_vc,
                        const float* __restrict__ w_h, const float* __restrict__ b_h,
                        float* __restrict__ hconst)
{
    __shared__ float vc[CH];
    int c = threadIdx.x;
    float s = 0.f;
    for (int ci = 0; ci < CH; ++ci) {
        const float* wp = w_vc + ((size_t)c * CH + ci) * 9;
        float ws = 0.f;
#pragma unroll
        for (int k = 0; k < 9; ++k) ws += wp[k];
        s += c0[ci] * ws;
    }
    vc[c] = s;
    __syncthreads();
    float hs = b_h[c];
    for (int ci = 0; ci < CH; ++ci) hs += w_h[(size_t)c * (3 * CH) + 2 * CH + ci] * vc[ci];
    hconst[c] = hs;
}

// ---------------------------------------------------------------------------
// weight cast/reorder: wq_r/wkv_r [co][tap*128+ci] (tap-major); whb [co][256];
// wob [co][128]; wxb [co][128]
// ---------------------------------------------------------------------------
__global__ void k_cast_w(const float* __restrict__ wq, const float* __restrict__ wk,
                         const float* __restrict__ wv, const float* __restrict__ wh,
                         const float* __restrict__ wo, const float* __restrict__ wx,
                         unsigned short* __restrict__ wq_r, unsigned short* __restrict__ wkv_r,
                         unsigned short* __restrict__ whb, unsigned short* __restrict__ wob,
                         unsigned short* __restrict__ wxb)
{
    int t = blockIdx.x * 256 + threadIdx.x;    // 0..147455
    int co = t / KC;
    int rem = t - co * KC;
    int tap = rem >> 7, ci = rem & 127;
    int iidx = co * KC + ci * 9 + tap;
    wq_r[t] = f2bf(wq[iidx]);
    wkv_r[t] = f2bf(wk[iidx]);
    wkv_r[147456 + t] = f2bf(wv[iidx]);
    if (t < 32768) {
        int c2 = t >> 8, k2 = t & 255;
        whb[t] = f2bf(wh[c2 * 384 + k2]);
    }
    if (t < 16384) { wob[t] = f2bf(wo[t]); wxb[t] = f2bf(wx[t]); }
}

// ---------------------------------------------------------------------------
// proj: x = w_x . inp + b_x, MFMA, per-wave 16 p x 128 co, K=128.
// A built on-the-fly from fp32 inp (read once, HBM). out xt[p][c] bf16.
// ---------------------------------------------------------------------------
__global__ __launch_bounds__(64)
void k_proj(const float* __restrict__ inp, const unsigned short* __restrict__ wxb,
            const float* __restrict__ bx, unsigned short* __restrict__ xt)
{
    const int lane = threadIdx.x;
    const int quad = lane >> 4, lrow = lane & 15;
    const int p0 = blockIdx.x * 16;             // 81 tiles, exact
    const int n = blockIdx.y;
    const float* in_n = inp + (size_t)n * CH * PP;
    f32x4 acc[8] = {};

#pragma unroll
    for (int ks = 0; ks < 4; ++ks) {
        union { short8 v; unsigned short u[8]; } a;
        int ci0 = ks * 32 + quad * 8;
#pragma unroll
        for (int j = 0; j < 8; ++j)
            a.u[j] = f2bf(in_n[(size_t)(ci0 + j) * PP + p0 + lrow]);
#pragma unroll
        for (int ni = 0; ni < 8; ++ni) {
            short8 b = *(const short8*)&wxb[(size_t)(ni * 16 + lrow) * CH + ks * 32 + quad * 8];
            acc[ni] = MFMA(a.v, b, acc[ni]);
        }
    }
    unsigned short* xn = xt + (size_t)n * PP * CH;
#pragma unroll
    for (int ni = 0; ni < 8; ++ni) {
        float bv = bx[ni * 16 + lrow];
#pragma unroll
        for (int r = 0; r < 4; ++r)
            xn[(size_t)(p0 + quad * 4 + r) * CH + ni * 16 + lrow] = f2bf(acc[ni][r] + bv);
    }
}

// ---------------------------------------------------------------------------
// q conv (3x3 SAME): per-wave 32 p x 128 co, K=1152 tap-major, fragments
// straight from global (xt patches contiguous in ci; weights [co][k]).
// ---------------------------------------------------------------------------
__global__ __launch_bounds__(64)
void k_conv_q(const unsigned short* __restrict__ xt, const unsigned short* __restrict__ wb,
              unsigned short* __restrict__ qt)
{
    const int lane = threadIdx.x;
    const int quad = lane >> 4, lrow = lane & 15;
    const int p0 = blockIdx.x * 32;             // 41 tiles
    const int n = blockIdx.y;
    const unsigned short* xn = xt + (size_t)n * PP * CH;

    int pr[2], pc[2];
#pragma unroll
    for (int mi = 0; mi < 2; ++mi) {
        int p = p0 + mi * 16 + lrow; if (p >= PP) p = PP - 1;
        pr[mi] = p / 36; pc[mi] = p - pr[mi] * 36;
    }
    f32x4 acc[2][8] = {};

    for (int ks = 0; ks < 36; ++ks) {
        int tap = ks >> 2;
        int ky = tap / 3, kx = tap - ky * 3;
        int ci0 = (ks & 3) * 32 + quad * 8;
        short8 a[2];
#pragma unroll
        for (int mi = 0; mi < 2; ++mi) {
            int yy = pr[mi] + ky - 1, xx = pc[mi] + kx - 1;
            short8 z; 
#pragma unroll
            for (int j = 0; j < 8; ++j) z[j] = 0;
            a[mi] = (yy >= 0 && yy < HH && xx >= 0 && xx < WWI)
                        ? *(const short8*)&xn[(size_t)(yy * WWI + xx) * CH + ci0] : z;
        }
#pragma unroll
        for (int ni = 0; ni < 8; ++ni) {
            short8 b = *(const short8*)&wb[(size_t)(ni * 16 + lrow) * KC + ks * 32 + quad * 8];
#pragma unroll
            for (int mi = 0; mi < 2; ++mi) acc[mi][ni] = MFMA(a[mi], b, acc[mi][ni]);
        }
    }

    unsigned short* qn = qt + (size_t)n * PP * CH;
#pragma unroll
    for (int mi = 0; mi < 2; ++mi)
#pragma unroll
        for (int r = 0; r < 4; ++r) {
            int p = p0 + mi * 16 + quad * 4 + r;
            if (p < PP) {
#pragma unroll
                for (int ni = 0; ni < 8; ++ni)
                    qn[(size_t)p * CH + ni * 16 + lrow] = f2bf(acc[mi][ni][r]);
            }
        }
}

// ---------------------------------------------------------------------------
// k+v conv (3x3 VALID) fused: per-wave 32 d x 256 co (k:0..127 -> kt[d][c],
// v:128..255 -> vb[c][d]), K=1152.
// ---------------------------------------------------------------------------
__global__ __launch_bounds__(64)
void k_conv_kv(const unsigned short* __restrict__ xt, const unsigned short* __restrict__ wb,
               unsigned short* __restrict__ kt, unsigned short* __restrict__ vb)
{
    const int lane = threadIdx.x;
    const int quad = lane >> 4, lrow = lane & 15;
    const int d0 = blockIdx.x * 32;             // 37 tiles
    const int n = blockIdx.y;
    const unsigned short* xn = xt + (size_t)n * PP * CH;

    int pr[2], pc[2];
#pragma unroll
    for (int mi = 0; mi < 2; ++mi) {
        int d = d0 + mi * 16 + lrow; if (d >= DD) d = DD - 1;
        pr[mi] = d / 34; pc[mi] = d - pr[mi] * 34;
    }
    f32x4 acc[2][16] = {};

    for (int ks = 0; ks < 36; ++ks) {
        int tap = ks >> 2;
        int ky = tap / 3, kx = tap - ky * 3;
        int ci0 = (ks & 3) * 32 + quad * 8;
        short8 a[2];
#pragma unroll
        for (int mi = 0; mi < 2; ++mi)
            a[mi] = *(const short8*)&xn[(size_t)((pr[mi] + ky) * WWI + pc[mi] + kx) * CH + ci0];
#pragma unroll
        for (int ni = 0; ni < 16; ++ni) {
            short8 b = *(const short8*)&wb[(size_t)(ni * 16 + lrow) * KC + ks * 32 + quad * 8];
#pragma unroll
            for (int mi = 0; mi < 2; ++mi) acc[mi][ni] = MFMA(a[mi], b, acc[mi][ni]);
        }
    }

    unsigned short* kn = kt + (size_t)n * DD * CH;
    unsigned short* vn = vb + (size_t)n * CH * VP;
#pragma unroll
    for (int mi = 0; mi < 2; ++mi)
#pragma unroll
        for (int r = 0; r < 4; ++r) {
            int d = d0 + mi * 16 + quad * 4 + r;
            if (d < DD) {
#pragma unroll
                for (int ni = 0; ni < 8; ++ni)
                    kn[(size_t)d * CH + ni * 16 + lrow] = f2bf(acc[mi][ni][r]);
#pragma unroll
                for (int ni = 8; ni < 16; ++ni)
                    vn[(size_t)((ni - 8) * 16 + lrow) * VP + d] = f2bf(acc[mi][ni][r]);
            }
        }
}

// ---------------------------------------------------------------------------
// flash attention, per-wave: 32 q rows, walk 10 d-tiles of 128. Fragments
// straight from global (kt[d][c], vb[c][d] are exact B layouts). Only LDS:
// wave-private P transpose (intra-wave waitcnt, no real barrier cost).
// ---------------------------------------------------------------------------
__global__ __launch_bounds__(64)
void k_attn(const unsigned short* __restrict__ qt, const unsigned short* __restrict__ kt,
            const unsigned short* __restrict__ vb, unsigned short* __restrict__ a0t)
{
    __shared__ unsigned short lp[32 * 136];
    const int lane = threadIdx.x;
    const int quad = lane >> 4, lrow = lane & 15;
    const int q0 = blockIdx.x * 32;             // 41 tiles
    const int n = blockIdx.y;
    const unsigned short* qn = qt + (size_t)n * PP * CH;
    const unsigned short* kn = kt + (size_t)n * DD * CH;
    const unsigned short* vn = vb + (size_t)n * CH * VP;

    short8 qa[2][4];
#pragma unroll
    for (int mi = 0; mi < 2; ++mi) {
        int q = q0 + mi * 16 + lrow; if (q >= PP) q = PP - 1;
#pragma unroll
        for (int ks = 0; ks < 4; ++ks)
            qa[mi][ks] = *(const short8*)&qn[(size_t)q * CH + ks * 32 + quad * 8];
    }

    f32x4 o[2][8] = {};
    float mm[2][4], ll[2][4];
#pragma unroll
    for (int mi = 0; mi < 2; ++mi)
#pragma unroll
        for (int r = 0; r < 4; ++r) { mm[mi][r] = -1e30f; ll[mi][r] = 0.f; }

    for (int dt = 0; dt < 10; ++dt) {
        const int d0 = dt * 128;
        // S = Q.K^T
        f32x4 s[2][8] = {};
#pragma unroll
        for (int ks = 0; ks < 4; ++ks)
#pragma unroll
            for (int ni = 0; ni < 8; ++ni) {
                int d = d0 + ni * 16 + lrow; if (d >= DD) d = DD - 1;
                short8 b = *(const short8*)&kn[(size_t)d * CH + ks * 32 + quad * 8];
#pragma unroll
                for (int mi = 0; mi < 2; ++mi) s[mi][ni] = MFMA(qa[mi][ks], b, s[mi][ni]);
            }
        // mask tail + online softmax
#pragma unroll
        for (int ni = 0; ni < 8; ++ni)
            if (d0 + ni * 16 + lrow >= DD)
#pragma unroll
                for (int mi = 0; mi < 2; ++mi)
#pragma unroll
                    for (int r = 0; r < 4; ++r) s[mi][ni][r] = -1e30f;

#pragma unroll
        for (int mi = 0; mi < 2; ++mi) {
            float mx[4] = {-1e30f, -1e30f, -1e30f, -1e30f};
#pragma unroll
            for (int ni = 0; ni < 8; ++ni)
#pragma unroll
                for (int r = 0; r < 4; ++r) mx[r] = fmaxf(mx[r], s[mi][ni][r]);
#pragma unroll
            for (int off = 1; off < 16; off <<= 1)
#pragma unroll
                for (int r = 0; r < 4; ++r) mx[r] = fmaxf(mx[r], __shfl_xor(mx[r], off, 64));
            float al[4], rs[4] = {0.f, 0.f, 0.f, 0.f};
#pragma unroll
            for (int r = 0; r < 4; ++r) {
                float mn = fmaxf(mm[mi][r], mx[r]);
                al[r] = __expf(mm[mi][r] - mn);
                mm[mi][r] = mn;
            }
#pragma unroll
            for (int ni = 0; ni < 8; ++ni)
#pragma unroll
                for (int r = 0; r < 4; ++r) {
                    float e = __expf(s[mi][ni][r] - mm[mi][r]);
                    s[mi][ni][r] = e;
                    rs[r] += e;
                }
#pragma unroll
            for (int off = 1; off < 16; off <<= 1)
#pragma unroll
                for (int r = 0; r < 4; ++r) rs[r] += __shfl_xor(rs[r], off, 64);
#pragma unroll
            for (int r = 0; r < 4; ++r) ll[mi][r] = ll[mi][r] * al[r] + rs[r];
#pragma unroll
            for (int ni = 0; ni < 8; ++ni)
#pragma unroll
                for (int r = 0; r < 4; ++r) o[mi][ni][r] *= al[r];
            // P -> LDS (transpose to A-operand layout)
#pragma unroll
            for (int ni = 0; ni < 8; ++ni)
#pragma unroll
                for (int r = 0; r < 4; ++r)
                    lp[(mi * 16 + quad * 4 + r) * 136 + ni * 16 + lrow] = f2bf(s[mi][ni][r]);
        }
        __syncthreads();   // single wave: compiles to lgkmcnt wait (+ cheap barrier)

        // O += P.V
#pragma unroll
        for (int ks = 0; ks < 4; ++ks) {
            short8 pa[2];
#pragma unroll
            for (int mi = 0; mi < 2; ++mi)
                pa[mi] = *(const short8*)&lp[(mi * 16 + lrow) * 136 + ks * 32 + quad * 8];
#pragma unroll
            for (int ni = 0; ni < 8; ++ni) {
                short8 b = *(const short8*)&vn[(size_t)(ni * 16 + lrow) * VP + d0 + ks * 32 + quad * 8];
#pragma unroll
                for (int mi = 0; mi < 2; ++mi) o[mi][ni] = MFMA(pa[mi], b, o[mi][ni]);
            }
        }
        __syncthreads();
    }

    unsigned short* an = a0t + (size_t)n * PP * CH;
#pragma unroll
    for (int mi = 0; mi < 2; ++mi) {
        float inv[4];
#pragma unroll
        for (int r = 0; r < 4; ++r) inv[r] = 1.f / ll[mi][r];
#pragma unroll
        for (int r = 0; r < 4; ++r) {
            int q = q0 + mi * 16 + quad * 4 + r;
            if (q < PP) {
#pragma unroll
                for (int ni = 0; ni < 8; ++ni)
                    an[(size_t)q * CH + ni * 16 + lrow] = f2bf(o[mi][ni][r] * inv[r]);
            }
        }
    }
}

// ---------------------------------------------------------------------------
// fused h + out: per-wave 32 p. GEMM1: h = tanh(whb.[xt;a0t] + hconst)
// (K=256) -> LDS transpose -> GEMM2: out = wob.h + b_o (K=128), fp32 store.
// ---------------------------------------------------------------------------
__global__ __launch_bounds__(64)
void k_hout(const unsigned short* __restrict__ xt, const unsigned short* __restrict__ a0t,
            const unsigned short* __restrict__ whb, const float* __restrict__ hconst,
            const unsigned short* __restrict__ wob, const float* __restrict__ bo,
            float* __restrict__ out)
{
    __shared__ unsigned short lh[32 * 136];
    const int lane = threadIdx.x;
    const int quad = lane >> 4, lrow = lane & 15;
    const int p0 = blockIdx.x * 32;             // 41 tiles
    const int n = blockIdx.y;
    const unsigned short* x0 = xt + (size_t)n * PP * CH;
    const unsigned short* a0 = a0t + (size_t)n * PP * CH;

    int pcl[2];
#pragma unroll
    for (int mi = 0; mi < 2; ++mi) {
        int p = p0 + mi * 16 + lrow; if (p >= PP) p = PP - 1;
        pcl[mi] = p;
    }

    f32x4 acc[2][8] = {};
#pragma unroll
    for (int ks = 0; ks < 8; ++ks) {
        short8 a[2];
        int col = (ks & 3) * 32 + quad * 8;
#pragma unroll
        for (int mi = 0; mi < 2; ++mi) {
            const unsigned short* src = (ks < 4) ? x0 : a0;
            a[mi] = *(const short8*)&src[(size_t)pcl[mi] * CH + col];
        }
#pragma unroll
        for (int ni = 0; ni < 8; ++ni) {
            short8 b = *(const short8*)&whb[(size_t)(ni * 16 + lrow) * 256 + ks * 32 + quad * 8];
#pragma unroll
            for (int mi = 0; mi < 2; ++mi) acc[mi][ni] = MFMA(a[mi], b, acc[mi][ni]);
        }
    }
    // tanh + write h tile to LDS [p][co]
#pragma unroll
    for (int ni = 0; ni < 8; ++ni) {
        float hc = hconst[ni * 16 + lrow];
#pragma unroll
        for (int mi = 0; mi < 2; ++mi)
#pragma unroll
            for (int r = 0; r < 4; ++r)
                lh[(mi * 16 + quad * 4 + r) * 136 + ni * 16 + lrow] = f2bf(fast_tanh(acc[mi][ni][r] + hc));
    }
    __syncthreads();   // single wave

    f32x4 acc2[2][8] = {};
#pragma unroll
    for (int ks = 0; ks < 4; ++ks) {
        short8 a[2];
#pragma unroll
        for (int mi = 0; mi < 2; ++mi)
            a[mi] = *(const short8*)&lh[(mi * 16 + lrow) * 136 + ks * 32 + quad * 8];
#pragma unroll
        for (int ni = 0; ni < 8; ++ni) {
            short8 b = *(const short8*)&wob[(size_t)(ni * 16 + lrow) * CH + ks * 32 + quad * 8];
#pragma unroll
            for (int mi = 0; mi < 2; ++mi) acc2[mi][ni] = MFMA(a[mi], b, acc2[mi][ni]);
        }
    }

#pragma unroll
    for (int ni = 0; ni < 8; ++ni) {
        float bv = bo[ni * 16 + lrow];
#pragma unroll
        for (int mi = 0; mi < 2; ++mi)
#pragma unroll
            for (int r = 0; r < 4; ++r) {
                int p = p0 + mi * 16 + quad * 4 + r;
                if (p < PP)
                    out[((size_t)(n * CH + ni * 16 + lrow)) * PP + p] = acc2[mi][ni][r] + bv;
            }
    }
}

// ---------------------------------------------------------------------------
extern "C" void kernel_launch(void* const* d_in, const int* in_sizes, int n_in,
                              void* d_out, int out_size, void* d_ws, size_t ws_size,
                              hipStream_t stream)
{
    const float* inp  = (const float*)d_in[0];
    const float* c0   = (const float*)d_in[1];
    const float* w_x  = (const float*)d_in[2];
    const float* b_x  = (const float*)d_in[3];
    const float* w_qx = (const float*)d_in[4];
    const float* w_kx = (const float*)d_in[6];
    const float* w_vx = (const float*)d_in[8];
    const float* w_vc = (const float*)d_in[9];
    const float* w_h  = (const float*)d_in[14];
    const float* b_h  = (const float*)d_in[15];
    const float* w_o  = (const float*)d_in[16];
    const float* b_o  = (const float*)d_in[17];
    float* out = (float*)d_out;

    char* w = (char*)d_ws;
    unsigned short* xt   = (unsigned short*)(w);             // 2,654,208 B
    unsigned short* qt   = (unsigned short*)(w + 2654208);   // 2,654,208 B
    unsigned short* kt   = (unsigned short*)(w + 5308416);   // 2,367,488 B
    unsigned short* vb   = (unsigned short*)(w + 7675904);   // 2,621,440 B
    unsigned short* a0t  = (unsigned short*)(w + 10297344);  // 2,654,208 B
    unsigned short* wxb  = (unsigned short*)(w + 12951552);  // 32,768 B
    unsigned short* wqr  = (unsigned short*)(w + 12984320);  // 294,912 B
    unsigned short* wkvr = (unsigned short*)(w + 13279232);  // 589,824 B
    unsigned short* whb  = (unsigned short*)(w + 13869056);  // 65,536 B
    unsigned short* wob  = (unsigned short*)(w + 13934592);  // 32,768 B
    float* hconst        = (float*)(w + 13967360);           // 512 B

    hipLaunchKernelGGL(k_const, dim3(1), dim3(128), 0, stream, c0, w_vc, w_h, b_h, hconst);
    hipLaunchKernelGGL(k_cast_w, dim3(576), dim3(256), 0, stream,
                       w_qx, w_kx, w_vx, w_h, w_o, w_x, wqr, wkvr, whb, wob, wxb);

    hipLaunchKernelGGL(k_proj, dim3(81, NN), dim3(64), 0, stream, inp, wxb, b_x, xt);

    hipLaunchKernelGGL(k_conv_q, dim3(41, NN), dim3(64), 0, stream, xt, wqr, qt);
    hipLaunchKernelGGL(k_conv_kv, dim3(37, NN), dim3(64), 0, stream, xt, wkvr, kt, vb);

    hipLaunchKernelGGL(k_attn, dim3(41, NN), dim3(64), 0, stream, qt, kt, vb, a0t);

    hipLaunchKernelGGL(k_hout, dim3(41, NN), dim3(64), 0, stream,
                       xt, a0t, whb, hconst, wob, b_o, out);
}

// Round 5
// 299.915 us; speedup vs baseline: 1.1401x; 1.1401x over previous
//
#include <hip/hip_runtime.h>
#include <hip/hip_bf16.h>
#include <math.h>

#define NN 8
#define CH 128
#define HH 36
#define WWI 36
#define PP 1296      // 36*36
#define DD 1156      // 34*34
#define VP 1280      // vb row pitch (shorts) — covers clamped d-tail reads
#define KC 1152      // 128*9

typedef __attribute__((ext_vector_type(8))) short short8;
typedef __attribute__((ext_vector_type(4))) float f32x4;

__device__ inline unsigned short f2bf(float f) {
    __hip_bfloat16 h = __float2bfloat16(f);
    return __builtin_bit_cast(unsigned short, h);
}
__device__ inline float fast_tanh(float x) {
    float e = __expf(2.f * x);
    return 1.f - 2.f / (e + 1.f);
}
#define MFMA(a, b, c) __builtin_amdgcn_mfma_f32_16x16x32_bf16((a), (b), (c), 0, 0, 0)

// ---------------------------------------------------------------------------
// hconst[co] = b_h[co] + sum_ci w_h[co,256+ci]*vc[ci]; vc = folded c-branch
// attention (spatially-uniform c => uniform softmax => constant v_c).
// ---------------------------------------------------------------------------
__global__ void k_const(const float* __restrict__ c0, const float* __restrict__ w_vc,
                        const float* __restrict__ w_h, const float* __restrict__ b_h,
                        float* __restrict__ hconst)
{
    __shared__ float vc[CH];
    int c = threadIdx.x;
    float s = 0.f;
    for (int ci = 0; ci < CH; ++ci) {
        const float* wp = w_vc + ((size_t)c * CH + ci) * 9;
        float ws = 0.f;
#pragma unroll
        for (int k = 0; k < 9; ++k) ws += wp[k];
        s += c0[ci] * ws;
    }
    vc[c] = s;
    __syncthreads();
    float hs = b_h[c];
    for (int ci = 0; ci < CH; ++ci) hs += w_h[(size_t)c * (3 * CH) + 2 * CH + ci] * vc[ci];
    hconst[c] = hs;
}

// ---------------------------------------------------------------------------
// weight cast/reorder: wq_r/wkv_r [co][tap*128+ci] (tap-major); whb [co][256];
// wob [co][128]; wxb [co][128]
// ---------------------------------------------------------------------------
__global__ void k_cast_w(const float* __restrict__ wq, const float* __restrict__ wk,
                         const float* __restrict__ wv, const float* __restrict__ wh,
                         const float* __restrict__ wo, const float* __restrict__ wx,
                         unsigned short* __restrict__ wq_r, unsigned short* __restrict__ wkv_r,
                         unsigned short* __restrict__ whb, unsigned short* __restrict__ wob,
                         unsigned short* __restrict__ wxb)
{
    int t = blockIdx.x * 256 + threadIdx.x;    // 0..147455
    int co = t / KC;
    int rem = t - co * KC;
    int tap = rem >> 7, ci = rem & 127;
    int iidx = co * KC + ci * 9 + tap;
    wq_r[t] = f2bf(wq[iidx]);
    wkv_r[t] = f2bf(wk[iidx]);
    wkv_r[147456 + t] = f2bf(wv[iidx]);
    if (t < 32768) {
        int c2 = t >> 8, k2 = t & 255;
        whb[t] = f2bf(wh[c2 * 384 + k2]);
    }
    if (t < 16384) { wob[t] = f2bf(wo[t]); wxb[t] = f2bf(wx[t]); }
}

// ---------------------------------------------------------------------------
// proj: x = w_x . inp + b_x. Per-wave 16 p x 128 co, K=128; A assembled
// on-the-fly from fp32 inp. out xt[p][c] bf16.
// ---------------------------------------------------------------------------
__global__ __launch_bounds__(64)
void k_proj(const float* __restrict__ inp, const unsigned short* __restrict__ wxb,
            const float* __restrict__ bx, unsigned short* __restrict__ xt)
{
    const int lane = threadIdx.x;
    const int quad = lane >> 4, lrow = lane & 15;
    const int p0 = blockIdx.x * 16;             // 81 tiles, exact
    const int n = blockIdx.y;
    const float* in_n = inp + (size_t)n * CH * PP;
    f32x4 acc[8] = {};

#pragma unroll
    for (int ks = 0; ks < 4; ++ks) {
        union { short8 v; unsigned short u[8]; } a;
        int ci0 = ks * 32 + quad * 8;
#pragma unroll
        for (int j = 0; j < 8; ++j)
            a.u[j] = f2bf(in_n[(size_t)(ci0 + j) * PP + p0 + lrow]);
#pragma unroll
        for (int ni = 0; ni < 8; ++ni) {
            short8 b = *(const short8*)&wxb[(size_t)(ni * 16 + lrow) * CH + ks * 32 + quad * 8];
            acc[ni] = MFMA(a.v, b, acc[ni]);
        }
    }
    unsigned short* xn = xt + (size_t)n * PP * CH;
#pragma unroll
    for (int ni = 0; ni < 8; ++ni) {
        float bv = bx[ni * 16 + lrow];
#pragma unroll
        for (int r = 0; r < 4; ++r)
            xn[(size_t)(p0 + quad * 4 + r) * CH + ni * 16 + lrow] = f2bf(acc[ni][r] + bv);
    }
}

// ---------------------------------------------------------------------------
// q conv (3x3 SAME): wave = 32 p x 64 co; block = 4 p-subtiles (128 p) x one
// co-group; weights read direct from global (L1-shared across waves).
// ---------------------------------------------------------------------------
__global__ __launch_bounds__(256)
void k_conv_q(const unsigned short* __restrict__ xt, const unsigned short* __restrict__ wb,
              unsigned short* __restrict__ qt)
{
    const int t = threadIdx.x;
    const int wave = t >> 6, lane = t & 63;
    const int quad = lane >> 4, lrow = lane & 15;
    const int p0 = blockIdx.x * 128 + wave * 32;
    const int g = blockIdx.y;                 // co group (2 x 64)
    const int n = blockIdx.z;
    const unsigned short* xn = xt + (size_t)n * PP * CH;

    int pr[2], pc[2];
#pragma unroll
    for (int mi = 0; mi < 2; ++mi) {
        int p = p0 + mi * 16 + lrow; if (p >= PP) p = PP - 1;
        pr[mi] = p / 36; pc[mi] = p - pr[mi] * 36;
    }
    f32x4 acc[2][4] = {};

    for (int ks = 0; ks < 36; ++ks) {
        int tap = ks >> 2;
        int ky = tap / 3, kx = tap - ky * 3;
        int ci0 = (ks & 3) * 32 + quad * 8;
        short8 a[2];
#pragma unroll
        for (int mi = 0; mi < 2; ++mi) {
            int yy = pr[mi] + ky - 1, xx = pc[mi] + kx - 1;
            short8 z;
#pragma unroll
            for (int j = 0; j < 8; ++j) z[j] = 0;
            a[mi] = (yy >= 0 && yy < HH && xx >= 0 && xx < WWI)
                        ? *(const short8*)&xn[(size_t)(yy * WWI + xx) * CH + ci0] : z;
        }
#pragma unroll
        for (int ni = 0; ni < 4; ++ni) {
            short8 b = *(const short8*)&wb[(size_t)(g * 64 + ni * 16 + lrow) * KC + ks * 32 + quad * 8];
#pragma unroll
            for (int mi = 0; mi < 2; ++mi) acc[mi][ni] = MFMA(a[mi], b, acc[mi][ni]);
        }
    }

    unsigned short* qn = qt + (size_t)n * PP * CH;
#pragma unroll
    for (int mi = 0; mi < 2; ++mi)
#pragma unroll
        for (int r = 0; r < 4; ++r) {
            int p = p0 + mi * 16 + quad * 4 + r;
            if (p < PP) {
#pragma unroll
                for (int ni = 0; ni < 4; ++ni)
                    qn[(size_t)p * CH + g * 64 + ni * 16 + lrow] = f2bf(acc[mi][ni][r]);
            }
        }
}

// ---------------------------------------------------------------------------
// k+v conv (3x3 VALID) fused over 256 output rows (k:0..127, v:128..255).
// wave = 32 d x 64 co-slice; block = 4 d-subtiles x one co-group (4 groups).
// ---------------------------------------------------------------------------
__global__ __launch_bounds__(256)
void k_conv_kv(const unsigned short* __restrict__ xt, const unsigned short* __restrict__ wb,
               unsigned short* __restrict__ kt, unsigned short* __restrict__ vb)
{
    const int t = threadIdx.x;
    const int wave = t >> 6, lane = t & 63;
    const int quad = lane >> 4, lrow = lane & 15;
    const int d0 = blockIdx.x * 128 + wave * 32;
    const int g = blockIdx.y;                 // co group (4 x 64 of 256)
    const int n = blockIdx.z;
    const unsigned short* xn = xt + (size_t)n * PP * CH;

    int pr[2], pc[2];
#pragma unroll
    for (int mi = 0; mi < 2; ++mi) {
        int d = d0 + mi * 16 + lrow; if (d >= DD) d = DD - 1;
        pr[mi] = d / 34; pc[mi] = d - pr[mi] * 34;
    }
    f32x4 acc[2][4] = {};

    for (int ks = 0; ks < 36; ++ks) {
        int tap = ks >> 2;
        int ky = tap / 3, kx = tap - ky * 3;
        int ci0 = (ks & 3) * 32 + quad * 8;
        short8 a[2];
#pragma unroll
        for (int mi = 0; mi < 2; ++mi)
            a[mi] = *(const short8*)&xn[(size_t)((pr[mi] + ky) * WWI + pc[mi] + kx) * CH + ci0];
#pragma unroll
        for (int ni = 0; ni < 4; ++ni) {
            short8 b = *(const short8*)&wb[(size_t)(g * 64 + ni * 16 + lrow) * KC + ks * 32 + quad * 8];
#pragma unroll
            for (int mi = 0; mi < 2; ++mi) acc[mi][ni] = MFMA(a[mi], b, acc[mi][ni]);
        }
    }

    unsigned short* kn = kt + (size_t)n * DD * CH;
    unsigned short* vn = vb + (size_t)n * CH * VP;
#pragma unroll
    for (int mi = 0; mi < 2; ++mi)
#pragma unroll
        for (int r = 0; r < 4; ++r) {
            int d = d0 + mi * 16 + quad * 4 + r;
            if (d < DD) {
                if (g < 2) {
#pragma unroll
                    for (int ni = 0; ni < 4; ++ni)
                        kn[(size_t)d * CH + g * 64 + ni * 16 + lrow] = f2bf(acc[mi][ni][r]);
                } else {
#pragma unroll
                    for (int ni = 0; ni < 4; ++ni)
                        vn[(size_t)((g - 2) * 64 + ni * 16 + lrow) * VP + d] = f2bf(acc[mi][ni][r]);
                }
            }
        }
}

// ---------------------------------------------------------------------------
// flash attention, d-split: block = 2 waves on the same 16 q rows; wave w
// walks d-tiles [5w, 5w+5). States merged through LDS at the end.
// ---------------------------------------------------------------------------
__global__ __launch_bounds__(128)
void k_attn(const unsigned short* __restrict__ qt, const unsigned short* __restrict__ kt,
            const unsigned short* __restrict__ vb, unsigned short* __restrict__ a0t)
{
    __shared__ unsigned short lp[2][16 * 136];
    __shared__ float lo[2][16 * 132];
    __shared__ float lm[2][16];
    __shared__ float lls[2][16];
    const int t = threadIdx.x;
    const int wave = t >> 6, lane = t & 63;
    const int quad = lane >> 4, lrow = lane & 15;
    const int q0 = blockIdx.x * 16;             // 81 tiles, exact
    const int n = blockIdx.y;
    const unsigned short* qn = qt + (size_t)n * PP * CH;
    const unsigned short* kn = kt + (size_t)n * DD * CH;
    const unsigned short* vn = vb + (size_t)n * CH * VP;

    short8 qa[4];
#pragma unroll
    for (int ks = 0; ks < 4; ++ks)
        qa[ks] = *(const short8*)&qn[(size_t)(q0 + lrow) * CH + ks * 32 + quad * 8];

    f32x4 o[8] = {};
    float mm[4] = {-1e30f, -1e30f, -1e30f, -1e30f};
    float ll[4] = {0.f, 0.f, 0.f, 0.f};

    for (int dt = 0; dt < 5; ++dt) {
        const int d0 = (wave * 5 + dt) * 128;
        // S = Q.K^T
        f32x4 s[8] = {};
#pragma unroll
        for (int ks = 0; ks < 4; ++ks)
#pragma unroll
            for (int ni = 0; ni < 8; ++ni) {
                int d = d0 + ni * 16 + lrow; if (d >= DD) d = DD - 1;
                short8 b = *(const short8*)&kn[(size_t)d * CH + ks * 32 + quad * 8];
                s[ni] = MFMA(qa[ks], b, s[ni]);
            }
        // tail mask + online softmax
#pragma unroll
        for (int ni = 0; ni < 8; ++ni)
            if (d0 + ni * 16 + lrow >= DD)
#pragma unroll
                for (int r = 0; r < 4; ++r) s[ni][r] = -1e30f;

        float mx[4] = {-1e30f, -1e30f, -1e30f, -1e30f};
#pragma unroll
        for (int ni = 0; ni < 8; ++ni)
#pragma unroll
            for (int r = 0; r < 4; ++r) mx[r] = fmaxf(mx[r], s[ni][r]);
#pragma unroll
        for (int off = 1; off < 16; off <<= 1)
#pragma unroll
            for (int r = 0; r < 4; ++r) mx[r] = fmaxf(mx[r], __shfl_xor(mx[r], off, 64));
        float al[4], rs[4] = {0.f, 0.f, 0.f, 0.f};
#pragma unroll
        for (int r = 0; r < 4; ++r) {
            float mn = fmaxf(mm[r], mx[r]);
            al[r] = __expf(mm[r] - mn);
            mm[r] = mn;
        }
#pragma unroll
        for (int ni = 0; ni < 8; ++ni)
#pragma unroll
            for (int r = 0; r < 4; ++r) {
                float e = __expf(s[ni][r] - mm[r]);
                s[ni][r] = e;
                rs[r] += e;
            }
#pragma unroll
        for (int off = 1; off < 16; off <<= 1)
#pragma unroll
            for (int r = 0; r < 4; ++r) rs[r] += __shfl_xor(rs[r], off, 64);
#pragma unroll
        for (int r = 0; r < 4; ++r) ll[r] = ll[r] * al[r] + rs[r];
#pragma unroll
        for (int ni = 0; ni < 8; ++ni)
#pragma unroll
            for (int r = 0; r < 4; ++r) o[ni][r] *= al[r];
        // P -> wave-private LDS (transpose to A layout)
#pragma unroll
        for (int ni = 0; ni < 8; ++ni)
#pragma unroll
            for (int r = 0; r < 4; ++r)
                lp[wave][(quad * 4 + r) * 136 + ni * 16 + lrow] = f2bf(s[ni][r]);
        __syncthreads();
        // O += P.V
#pragma unroll
        for (int ks = 0; ks < 4; ++ks) {
            short8 pa = *(const short8*)&lp[wave][lrow * 136 + ks * 32 + quad * 8];
#pragma unroll
            for (int ni = 0; ni < 8; ++ni) {
                short8 b = *(const short8*)&vn[(size_t)(ni * 16 + lrow) * VP + d0 + ks * 32 + quad * 8];
                o[ni] = MFMA(pa, b, o[ni]);
            }
        }
        __syncthreads();
    }

    // merge the two d-half states
    if (lrow == 0)
#pragma unroll
        for (int r = 0; r < 4; ++r) lm[wave][quad * 4 + r] = mm[r];
    __syncthreads();
    float alpha[4], lpr[4];
#pragma unroll
    for (int r = 0; r < 4; ++r) {
        float mo = lm[1 - wave][quad * 4 + r];
        float mg = fmaxf(mm[r], mo);
        alpha[r] = __expf(mm[r] - mg);
        lpr[r] = ll[r] * alpha[r];
    }
    if (lrow == 0)
#pragma unroll
        for (int r = 0; r < 4; ++r) lls[wave][quad * 4 + r] = lpr[r];
#pragma unroll
    for (int ni = 0; ni < 8; ++ni)
#pragma unroll
        for (int r = 0; r < 4; ++r)
            lo[wave][(quad * 4 + r) * 132 + ni * 16 + lrow] = o[ni][r] * alpha[r];
    __syncthreads();

    unsigned short* an = a0t + (size_t)n * PP * CH;
#pragma unroll
    for (int ni2 = 0; ni2 < 4; ++ni2) {
        int col = (wave * 4 + ni2) * 16 + lrow;
#pragma unroll
        for (int r = 0; r < 4; ++r) {
            int row = quad * 4 + r;
            float sum = lo[0][row * 132 + col] + lo[1][row * 132 + col];
            float l = lls[0][row] + lls[1][row];
            an[(size_t)(q0 + row) * CH + col] = f2bf(sum / l);
        }
    }
}

// ---------------------------------------------------------------------------
// fused h+out, wave = 16 p: GEMM1 h=tanh(whb.[xt;a0t]+hconst) (K=256) ->
// LDS transpose -> GEMM2 out = wob.h + b_o (K=128), fp32 store.
// ---------------------------------------------------------------------------
__global__ __launch_bounds__(64)
void k_hout(const unsigned short* __restrict__ xt, const unsigned short* __restrict__ a0t,
            const unsigned short* __restrict__ whb, const float* __restrict__ hconst,
            const unsigned short* __restrict__ wob, const float* __restrict__ bo,
            float* __restrict__ out)
{
    __shared__ unsigned short lh[16 * 136];
    const int lane = threadIdx.x;
    const int quad = lane >> 4, lrow = lane & 15;
    const int p0 = blockIdx.x * 16;             // 81 tiles, exact
    const int n = blockIdx.y;
    const unsigned short* x0 = xt + (size_t)n * PP * CH;
    const unsigned short* a0 = a0t + (size_t)n * PP * CH;

    f32x4 acc[8] = {};
#pragma unroll
    for (int ks = 0; ks < 8; ++ks) {
        int col = (ks & 3) * 32 + quad * 8;
        const unsigned short* src = (ks < 4) ? x0 : a0;
        short8 a = *(const short8*)&src[(size_t)(p0 + lrow) * CH + col];
#pragma unroll
        for (int ni = 0; ni < 8; ++ni) {
            short8 b = *(const short8*)&whb[(size_t)(ni * 16 + lrow) * 256 + ks * 32 + quad * 8];
            acc[ni] = MFMA(a, b, acc[ni]);
        }
    }
#pragma unroll
    for (int ni = 0; ni < 8; ++ni) {
        float hc = hconst[ni * 16 + lrow];
#pragma unroll
        for (int r = 0; r < 4; ++r)
            lh[(quad * 4 + r) * 136 + ni * 16 + lrow] = f2bf(fast_tanh(acc[ni][r] + hc));
    }
    __syncthreads();   // single wave: waitcnt + cheap barrier

    f32x4 acc2[8] = {};
#pragma unroll
    for (int ks = 0; ks < 4; ++ks) {
        short8 a = *(const short8*)&lh[lrow * 136 + ks * 32 + quad * 8];
#pragma unroll
        for (int ni = 0; ni < 8; ++ni) {
            short8 b = *(const short8*)&wob[(size_t)(ni * 16 + lrow) * CH + ks * 32 + quad * 8];
            acc2[ni] = MFMA(a, b, acc2[ni]);
        }
    }
#pragma unroll
    for (int ni = 0; ni < 8; ++ni) {
        float bv = bo[ni * 16 + lrow];
#pragma unroll
        for (int r = 0; r < 4; ++r)
            out[((size_t)(n * CH + ni * 16 + lrow)) * PP + p0 + quad * 4 + r] = acc2[ni][r] + bv;
    }
}

// ---------------------------------------------------------------------------
extern "C" void kernel_launch(void* const* d_in, const int* in_sizes, int n_in,
                              void* d_out, int out_size, void* d_ws, size_t ws_size,
                              hipStream_t stream)
{
    const float* inp  = (const float*)d_in[0];
    const float* c0   = (const float*)d_in[1];
    const float* w_x  = (const float*)d_in[2];
    const float* b_x  = (const float*)d_in[3];
    const float* w_qx = (const float*)d_in[4];
    const float* w_kx = (const float*)d_in[6];
    const float* w_vx = (const float*)d_in[8];
    const float* w_vc = (const float*)d_in[9];
    const float* w_h  = (const float*)d_in[14];
    const float* b_h  = (const float*)d_in[15];
    const float* w_o  = (const float*)d_in[16];
    const float* b_o  = (const float*)d_in[17];
    float* out = (float*)d_out;

    char* w = (char*)d_ws;
    unsigned short* xt   = (unsigned short*)(w);             // 2,654,208 B
    unsigned short* qt   = (unsigned short*)(w + 2654208);   // 2,654,208 B
    unsigned short* kt   = (unsigned short*)(w + 5308416);   // 2,367,488 B
    unsigned short* vb   = (unsigned short*)(w + 7675904);   // 2,621,440 B
    unsigned short* a0t  = (unsigned short*)(w + 10297344);  // 2,654,208 B
    unsigned short* wxb  = (unsigned short*)(w + 12951552);  // 32,768 B
    unsigned short* wqr  = (unsigned short*)(w + 12984320);  // 294,912 B
    unsigned short* wkvr = (unsigned short*)(w + 13279232);  // 589,824 B
    unsigned short* whb  = (unsigned short*)(w + 13869056);  // 65,536 B
    unsigned short* wob  = (unsigned short*)(w + 13934592);  // 32,768 B
    float* hconst        = (float*)(w + 13967360);           // 512 B

    hipLaunchKernelGGL(k_const, dim3(1), dim3(128), 0, stream, c0, w_vc, w_h, b_h, hconst);
    hipLaunchKernelGGL(k_cast_w, dim3(576), dim3(256), 0, stream,
                       w_qx, w_kx, w_vx, w_h, w_o, w_x, wqr, wkvr, whb, wob, wxb);

    hipLaunchKernelGGL(k_proj, dim3(81, NN), dim3(64), 0, stream, inp, wxb, b_x, xt);

    hipLaunchKernelGGL(k_conv_q, dim3(11, 2, NN), dim3(256), 0, stream, xt, wqr, qt);
    hipLaunchKernelGGL(k_conv_kv, dim3(10, 4, NN), dim3(256), 0, stream, xt, wkvr, kt, vb);

    hipLaunchKernelGGL(k_attn, dim3(81, NN), dim3(128), 0, stream, qt, kt, vb, a0t);

    hipLaunchKernelGGL(k_hout, dim3(81, NN), dim3(64), 0, stream,
                       xt, a0t, whb, hconst, wob, b_o, out);
}

// Round 6
// 296.214 us; speedup vs baseline: 1.1543x; 1.0125x over previous
//
#include <hip/hip_runtime.h>
#include <hip/hip_bf16.h>
#include <math.h>

#define NN 8
#define CH 128
#define HH 36
#define WWI 36
#define PP 1296      // 36*36
#define DD 1156      // 34*34
#define VP 1280      // vb row pitch (shorts) — covers d-tail fragment reads
#define KC 1152      // 128*9
#define QT 81        // q tiles of 16
#define DT 10        // d tiles of 128

typedef __attribute__((ext_vector_type(8))) short short8;
typedef __attribute__((ext_vector_type(4))) float f32x4;

__device__ inline unsigned short f2bf(float f) {
    __hip_bfloat16 h = __float2bfloat16(f);
    return __builtin_bit_cast(unsigned short, h);
}
__device__ inline float fast_tanh(float x) {
    float e = __expf(2.f * x);
    return 1.f - 2.f / (e + 1.f);
}
#define MFMA(a, b, c) __builtin_amdgcn_mfma_f32_16x16x32_bf16((a), (b), (c), 0, 0, 0)

// ---------------------------------------------------------------------------
// setup: weight cast/reorder + folded constants.
//  wcat[384][1152]: rows 0..127 = wq, 128..255 = wk, 256..383 = wv,
//  K reordered tap-major (k = tap*128 + ci) so conv staging is uint4 loads.
//  whb[128][256] = w_h[:, :256]; wob/wxb [128][128].
//  hconst[co] = b_h + w_h[:,256:384].vc  (c-branch attention folds to const:
//  spatially-uniform c => uniform softmax => v_c constant).
// ---------------------------------------------------------------------------
__global__ void k_setup(const float* __restrict__ wq, const float* __restrict__ wk,
                        const float* __restrict__ wv, const float* __restrict__ wh,
                        const float* __restrict__ wo, const float* __restrict__ wx,
                        const float* __restrict__ c0, const float* __restrict__ w_vc,
                        const float* __restrict__ b_h,
                        unsigned short* __restrict__ wcat, unsigned short* __restrict__ whb,
                        unsigned short* __restrict__ wob, unsigned short* __restrict__ wxb,
                        float* __restrict__ hconst)
{
    if (blockIdx.x == 576) {
        __shared__ float vc[CH];
        int c = threadIdx.x;
        if (c < CH) {
            float s = 0.f;
            for (int ci = 0; ci < CH; ++ci) {
                const float* wp = w_vc + ((size_t)c * CH + ci) * 9;
                float ws = 0.f;
#pragma unroll
                for (int k = 0; k < 9; ++k) ws += wp[k];
                s += c0[ci] * ws;
            }
            vc[c] = s;
        }
        __syncthreads();
        if (c < CH) {
            float hs = b_h[c];
            for (int ci = 0; ci < CH; ++ci) hs += wh[(size_t)c * 384 + 256 + ci] * vc[ci];
            hconst[c] = hs;
        }
        return;
    }
    int t = blockIdx.x * 256 + threadIdx.x;    // 0..147455
    int co = t / KC;
    int rem = t - co * KC;
    int tap = rem >> 7, ci = rem & 127;
    int iidx = co * KC + ci * 9 + tap;
    wcat[t] = f2bf(wq[iidx]);
    wcat[147456 + t] = f2bf(wk[iidx]);
    wcat[294912 + t] = f2bf(wv[iidx]);
    if (t < 32768) {
        int c2 = t >> 8, k2 = t & 255;
        whb[t] = f2bf(wh[c2 * 384 + k2]);
    }
    if (t < 16384) { wob[t] = f2bf(wo[t]); wxb[t] = f2bf(wx[t]); }
}

// ---------------------------------------------------------------------------
// proj: x = w_x . inp + b_x. Wave = 16 p x 64 co, K=128; A assembled
// on-the-fly from fp32 inp. Grid (81, 2 co-groups, 8) = 1296 waves.
// ---------------------------------------------------------------------------
__global__ __launch_bounds__(64)
void k_proj(const float* __restrict__ inp, const unsigned short* __restrict__ wxb,
            const float* __restrict__ bx, unsigned short* __restrict__ xt)
{
    const int lane = threadIdx.x;
    const int quad = lane >> 4, lrow = lane & 15;
    const int p0 = blockIdx.x * 16;
    const int co0 = blockIdx.y * 64;
    const int n = blockIdx.z;
    const float* in_n = inp + (size_t)n * CH * PP;
    f32x4 acc[4] = {};

#pragma unroll
    for (int ks = 0; ks < 4; ++ks) {
        union { short8 v; unsigned short u[8]; } a;
        int ci0 = ks * 32 + quad * 8;
#pragma unroll
        for (int j = 0; j < 8; ++j)
            a.u[j] = f2bf(in_n[(size_t)(ci0 + j) * PP + p0 + lrow]);
#pragma unroll
        for (int ni = 0; ni < 4; ++ni) {
            short8 b = *(const short8*)&wxb[(size_t)(co0 + ni * 16 + lrow) * CH + ks * 32 + quad * 8];
            acc[ni] = MFMA(a.v, b, acc[ni]);
        }
    }
    unsigned short* xn = xt + (size_t)n * PP * CH;
#pragma unroll
    for (int ni = 0; ni < 4; ++ni) {
        float bv = bx[co0 + ni * 16 + lrow];
#pragma unroll
        for (int r = 0; r < 4; ++r)
            xn[(size_t)(p0 + quad * 4 + r) * CH + co0 + ni * 16 + lrow] = f2bf(acc[ni][r] + bv);
    }
}

// ---------------------------------------------------------------------------
// fused q/k/v conv. Wave = 32 tokens x 32 co. blockIdx.y in 0..11:
// y>>2: 0=q(SAME,1296 out), 1=k(VALID,1156), 2=v(VALID,1156); co0=(y&3)*32;
// weight row = y*32.. in wcat. Grid (11, 12, 8), 4 waves/block.
// ---------------------------------------------------------------------------
__global__ __launch_bounds__(256)
void k_conv(const unsigned short* __restrict__ xt, const unsigned short* __restrict__ wcat,
            unsigned short* __restrict__ qt, unsigned short* __restrict__ kt,
            unsigned short* __restrict__ vb)
{
    const int t = threadIdx.x;
    const int wave = t >> 6, lane = t & 63;
    const int quad = lane >> 4, lrow = lane & 15;
    const int y = blockIdx.y;
    const int mode = y >> 2;
    const int co0 = (y & 3) * 32;
    const int n = blockIdx.z;
    const int out0 = blockIdx.x * 128 + wave * 32;
    const int limit = (mode == 0) ? PP : DD;
    if (out0 >= limit) return;
    const unsigned short* xn = xt + (size_t)n * PP * CH;
    const int wrow0 = y * 32;

    int pr[2], pc[2];
#pragma unroll
    for (int mi = 0; mi < 2; ++mi) {
        int tok = out0 + mi * 16 + lrow; if (tok >= limit) tok = limit - 1;
        int dvs = (mode == 0) ? 36 : 34;
        pr[mi] = tok / dvs; pc[mi] = tok - pr[mi] * dvs;
    }
    f32x4 acc[2][2] = {};

#pragma unroll
    for (int ks = 0; ks < 36; ++ks) {
        int tap = ks >> 2;
        int ky = tap / 3, kx = tap - ky * 3;
        int ci0 = (ks & 3) * 32 + quad * 8;
        short8 a[2];
        if (mode == 0) {
#pragma unroll
            for (int mi = 0; mi < 2; ++mi) {
                int yy = pr[mi] + ky - 1, xx = pc[mi] + kx - 1;
                short8 z;
#pragma unroll
                for (int j = 0; j < 8; ++j) z[j] = 0;
                a[mi] = (yy >= 0 && yy < HH && xx >= 0 && xx < WWI)
                            ? *(const short8*)&xn[(size_t)(yy * WWI + xx) * CH + ci0] : z;
            }
        } else {
#pragma unroll
            for (int mi = 0; mi < 2; ++mi)
                a[mi] = *(const short8*)&xn[(size_t)((pr[mi] + ky) * WWI + pc[mi] + kx) * CH + ci0];
        }
#pragma unroll
        for (int ni = 0; ni < 2; ++ni) {
            short8 b = *(const short8*)&wcat[(size_t)(wrow0 + ni * 16 + lrow) * KC + ks * 32 + quad * 8];
#pragma unroll
            for (int mi = 0; mi < 2; ++mi) acc[mi][ni] = MFMA(a[mi], b, acc[mi][ni]);
        }
    }

    if (mode == 0) {
        unsigned short* qn = qt + (size_t)n * PP * CH;
#pragma unroll
        for (int mi = 0; mi < 2; ++mi)
#pragma unroll
            for (int r = 0; r < 4; ++r) {
                int p = out0 + mi * 16 + quad * 4 + r;
                if (p < PP)
#pragma unroll
                    for (int ni = 0; ni < 2; ++ni)
                        qn[(size_t)p * CH + co0 + ni * 16 + lrow] = f2bf(acc[mi][ni][r]);
            }
    } else if (mode == 1) {
        unsigned short* kn = kt + (size_t)n * DD * CH;
#pragma unroll
        for (int mi = 0; mi < 2; ++mi)
#pragma unroll
            for (int r = 0; r < 4; ++r) {
                int d = out0 + mi * 16 + quad * 4 + r;
                if (d < DD)
#pragma unroll
                    for (int ni = 0; ni < 2; ++ni)
                        kn[(size_t)d * CH + co0 + ni * 16 + lrow] = f2bf(acc[mi][ni][r]);
            }
    } else {
        unsigned short* vn = vb + (size_t)n * CH * VP;
#pragma unroll
        for (int mi = 0; mi < 2; ++mi)
#pragma unroll
            for (int r = 0; r < 4; ++r) {
                int d = out0 + mi * 16 + quad * 4 + r;
                if (d < DD)
#pragma unroll
                    for (int ni = 0; ni < 2; ++ni)
                        vn[(size_t)(co0 + ni * 16 + lrow) * VP + d] = f2bf(acc[mi][ni][r]);
            }
    }
}

// ---------------------------------------------------------------------------
// partial attention: ONE wave per (q16-tile, d128-tile). Plain partial
// softmax (no online rescale): m,l per row + O = P.V, stored fp16/fp32.
// Grid (81, 10, 8) = 6480 waves.
// ---------------------------------------------------------------------------
__global__ __launch_bounds__(64)
void k_attn(const unsigned short* __restrict__ qt, const unsigned short* __restrict__ kt,
            const unsigned short* __restrict__ vb, _Float16* __restrict__ po,
            float* __restrict__ pm, float* __restrict__ pl)
{
    __shared__ unsigned short lp[16 * 136];
    const int lane = threadIdx.x;
    const int quad = lane >> 4, lrow = lane & 15;
    const int qti = blockIdx.x;
    const int dt = blockIdx.y;
    const int n = blockIdx.z;
    const int q0 = qti * 16, d0 = dt * 128;
    const unsigned short* qn = qt + (size_t)n * PP * CH;
    const unsigned short* kn = kt + (size_t)n * DD * CH;
    const unsigned short* vn = vb + (size_t)n * CH * VP;

    short8 qa[4];
#pragma unroll
    for (int ks = 0; ks < 4; ++ks)
        qa[ks] = *(const short8*)&qn[(size_t)(q0 + lrow) * CH + ks * 32 + quad * 8];

    // S = Q.K^T
    f32x4 s[8] = {};
#pragma unroll
    for (int ks = 0; ks < 4; ++ks)
#pragma unroll
        for (int ni = 0; ni < 8; ++ni) {
            int d = d0 + ni * 16 + lrow; if (d >= DD) d = DD - 1;
            short8 b = *(const short8*)&kn[(size_t)d * CH + ks * 32 + quad * 8];
            s[ni] = MFMA(qa[ks], b, s[ni]);
        }
    // tail mask + row max
#pragma unroll
    for (int ni = 0; ni < 8; ++ni)
        if (d0 + ni * 16 + lrow >= DD)
#pragma unroll
            for (int r = 0; r < 4; ++r) s[ni][r] = -1e30f;

    float mx[4] = {-1e30f, -1e30f, -1e30f, -1e30f};
#pragma unroll
    for (int ni = 0; ni < 8; ++ni)
#pragma unroll
        for (int r = 0; r < 4; ++r) mx[r] = fmaxf(mx[r], s[ni][r]);
#pragma unroll
    for (int off = 1; off < 16; off <<= 1)
#pragma unroll
        for (int r = 0; r < 4; ++r) mx[r] = fmaxf(mx[r], __shfl_xor(mx[r], off, 64));

    float rs[4] = {0.f, 0.f, 0.f, 0.f};
#pragma unroll
    for (int ni = 0; ni < 8; ++ni)
#pragma unroll
        for (int r = 0; r < 4; ++r) {
            float e = __expf(s[ni][r] - mx[r]);
            s[ni][r] = e;
            rs[r] += e;
        }
#pragma unroll
    for (int off = 1; off < 16; off <<= 1)
#pragma unroll
        for (int r = 0; r < 4; ++r) rs[r] += __shfl_xor(rs[r], off, 64);

    // P -> LDS (transpose C-layout -> A-layout), single wave
#pragma unroll
    for (int ni = 0; ni < 8; ++ni)
#pragma unroll
        for (int r = 0; r < 4; ++r)
            lp[(quad * 4 + r) * 136 + ni * 16 + lrow] = f2bf(s[ni][r]);
    __syncthreads();

    // O = P.V
    f32x4 o[8] = {};
#pragma unroll
    for (int ks = 0; ks < 4; ++ks) {
        short8 pa = *(const short8*)&lp[lrow * 136 + ks * 32 + quad * 8];
#pragma unroll
        for (int ni = 0; ni < 8; ++ni) {
            short8 b = *(const short8*)&vn[(size_t)(ni * 16 + lrow) * VP + d0 + ks * 32 + quad * 8];
            o[ni] = MFMA(pa, b, o[ni]);
        }
    }

    const int base = (n * QT + qti) * DT + dt;
    _Float16* pob = po + (size_t)base * 2048;
#pragma unroll
    for (int ni = 0; ni < 8; ++ni)
#pragma unroll
        for (int r = 0; r < 4; ++r)
            pob[(quad * 4 + r) * 128 + ni * 16 + lrow] = (_Float16)o[ni][r];
    if (lrow == 0)
#pragma unroll
        for (int r = 0; r < 4; ++r) {
            pm[base * 16 + quad * 4 + r] = mx[r];
            pl[base * 16 + quad * 4 + r] = rs[r];
        }
}

// ---------------------------------------------------------------------------
// attention reduce: merge 10 d-tile partials per q16-tile. Grid (81, 8),
// 256 threads. Coalesced fp16 reads, bf16 a0t[q][c] out.
// ---------------------------------------------------------------------------
__global__ __launch_bounds__(256)
void k_ared(const _Float16* __restrict__ po, const float* __restrict__ pm,
            const float* __restrict__ pl, unsigned short* __restrict__ a0t)
{
    __shared__ float sm[160], ssc[160], smg[16], sli[16];
    const int qti = blockIdx.x;
    const int n = blockIdx.y;
    const int base = (n * QT + qti) * DT;
    const int t = threadIdx.x;
    if (t < 160) sm[t] = pm[base * 16 + t];
    __syncthreads();
    if (t < 16) {
        float mg = -1e30f;
#pragma unroll
        for (int dt = 0; dt < DT; ++dt) mg = fmaxf(mg, sm[dt * 16 + t]);
        float ls = 0.f;
#pragma unroll
        for (int dt = 0; dt < DT; ++dt) ls += __expf(sm[dt * 16 + t] - mg) * pl[base * 16 + dt * 16 + t];
        smg[t] = mg; sli[t] = 1.f / ls;
    }
    __syncthreads();
    if (t < 160) ssc[t] = __expf(sm[t] - smg[t & 15]);
    __syncthreads();

    unsigned short* an = a0t + (size_t)n * PP * CH;
#pragma unroll
    for (int k = 0; k < 8; ++k) {
        int idx = t + k * 256;
        int row = idx >> 7, c = idx & 127;
        float acc = 0.f;
#pragma unroll
        for (int dt = 0; dt < DT; ++dt)
            acc += ssc[dt * 16 + row] * (float)po[(size_t)(base + dt) * 2048 + idx];
        an[(size_t)(qti * 16 + row) * CH + c] = f2bf(acc * sli[row]);
    }
}

// ---------------------------------------------------------------------------
// fused h+out: 4 waves per 16-p tile. Wave w: GEMM1 co-slice {2w,2w+1}x16 of
// h=tanh(whb.[xt;a0t]+hconst) -> lh -> barrier -> GEMM2 co-slice of
// out = wob.h + b_o (fp32). Grid (81, 8) = 2592 waves.
// ---------------------------------------------------------------------------
__global__ __launch_bounds__(256)
void k_hout(const unsigned short* __restrict__ xt, const unsigned short* __restrict__ a0t,
            const unsigned short* __restrict__ whb, const float* __restrict__ hconst,
            const unsigned short* __restrict__ wob, const float* __restrict__ bo,
            float* __restrict__ out)
{
    __shared__ unsigned short lh[16 * 136];
    const int t = threadIdx.x;
    const int wave = t >> 6, lane = t & 63;
    const int quad = lane >> 4, lrow = lane & 15;
    const int p0 = blockIdx.x * 16;
    const int n = blockIdx.y;
    const unsigned short* x0 = xt + (size_t)n * PP * CH;
    const unsigned short* a0 = a0t + (size_t)n * PP * CH;

    f32x4 acc[2] = {};
#pragma unroll
    for (int ks = 0; ks < 8; ++ks) {
        int col = (ks & 3) * 32 + quad * 8;
        const unsigned short* src = (ks < 4) ? x0 : a0;
        short8 a = *(const short8*)&src[(size_t)(p0 + lrow) * CH + col];
#pragma unroll
        for (int j = 0; j < 2; ++j) {
            int ni = wave * 2 + j;
            short8 b = *(const short8*)&whb[(size_t)(ni * 16 + lrow) * 256 + ks * 32 + quad * 8];
            acc[j] = MFMA(a, b, acc[j]);
        }
    }
#pragma unroll
    for (int j = 0; j < 2; ++j) {
        int ni = wave * 2 + j;
        float hc = hconst[ni * 16 + lrow];
#pragma unroll
        for (int r = 0; r < 4; ++r)
            lh[(quad * 4 + r) * 136 + ni * 16 + lrow] = f2bf(fast_tanh(acc[j][r] + hc));
    }
    __syncthreads();

    f32x4 acc2[2] = {};
#pragma unroll
    for (int ks = 0; ks < 4; ++ks) {
        short8 a = *(const short8*)&lh[lrow * 136 + ks * 32 + quad * 8];
#pragma unroll
        for (int j = 0; j < 2; ++j) {
            int ni = wave * 2 + j;
            short8 b = *(const short8*)&wob[(size_t)(ni * 16 + lrow) * CH + ks * 32 + quad * 8];
            acc2[j] = MFMA(a, b, acc2[j]);
        }
    }
#pragma unroll
    for (int j = 0; j < 2; ++j) {
        int ni = wave * 2 + j;
        float bv = bo[ni * 16 + lrow];
#pragma unroll
        for (int r = 0; r < 4; ++r)
            out[((size_t)(n * CH + ni * 16 + lrow)) * PP + p0 + quad * 4 + r] = acc2[j][r] + bv;
    }
}

// ---------------------------------------------------------------------------
extern "C" void kernel_launch(void* const* d_in, const int* in_sizes, int n_in,
                              void* d_out, int out_size, void* d_ws, size_t ws_size,
                              hipStream_t stream)
{
    const float* inp  = (const float*)d_in[0];
    const float* c0   = (const float*)d_in[1];
    const float* w_x  = (const float*)d_in[2];
    const float* b_x  = (const float*)d_in[3];
    const float* w_qx = (const float*)d_in[4];
    const float* w_kx = (const float*)d_in[6];
    const float* w_vx = (const float*)d_in[8];
    const float* w_vc = (const float*)d_in[9];
    const float* w_h  = (const float*)d_in[14];
    const float* b_h  = (const float*)d_in[15];
    const float* w_o  = (const float*)d_in[16];
    const float* b_o  = (const float*)d_in[17];
    float* out = (float*)d_out;

    char* w = (char*)d_ws;
    unsigned short* xt   = (unsigned short*)(w);             // 2,654,208
    unsigned short* qt   = (unsigned short*)(w + 2654208);   // 2,654,208
    unsigned short* kt   = (unsigned short*)(w + 5308416);   // 2,367,488
    unsigned short* vb   = (unsigned short*)(w + 7675904);   // 2,621,440
    unsigned short* a0t  = (unsigned short*)(w + 10297344);  // 2,654,208
    unsigned short* wcat = (unsigned short*)(w + 12951552);  // 884,736
    unsigned short* wxb  = (unsigned short*)(w + 13836288);  // 32,768
    unsigned short* whb  = (unsigned short*)(w + 13869056);  // 65,536
    unsigned short* wob  = (unsigned short*)(w + 13934592);  // 32,768
    float* hconst        = (float*)(w + 13967360);           // 512
    float* pm            = (float*)(w + 13967872);           // 414,720
    float* pl            = (float*)(w + 14382592);           // 414,720
    _Float16* po         = (_Float16*)(w + 14797312);        // 26,542,080 -> 41.3 MB total

    hipLaunchKernelGGL(k_setup, dim3(577), dim3(256), 0, stream,
                       w_qx, w_kx, w_vx, w_h, w_o, w_x, c0, w_vc, b_h,
                       wcat, whb, wob, wxb, hconst);

    hipLaunchKernelGGL(k_proj, dim3(81, 2, NN), dim3(64), 0, stream, inp, wxb, b_x, xt);

    hipLaunchKernelGGL(k_conv, dim3(11, 12, NN), dim3(256), 0, stream, xt, wcat, qt, kt, vb);

    hipLaunchKernelGGL(k_attn, dim3(QT, DT, NN), dim3(64), 0, stream, qt, kt, vb, po, pm, pl);
    hipLaunchKernelGGL(k_ared, dim3(QT, NN), dim3(256), 0, stream, po, pm, pl, a0t);

    hipLaunchKernelGGL(k_hout, dim3(QT, NN), dim3(256), 0, stream,
                       xt, a0t, whb, hconst, wob, b_o, out);
}

// Round 9
// 294.955 us; speedup vs baseline: 1.1592x; 1.0043x over previous
//
#include <hip/hip_runtime.h>
#include <hip/hip_bf16.h>
#include <math.h>

#define NN 8
#define CH 128
#define HH 36
#define WWI 36
#define PP 1296      // 36*36
#define DD 1156      // 34*34
#define VP 1280      // vb row pitch (shorts) — covers d-tail fragment reads
#define KC 1152      // 128*9
#define QT 81        // q tiles of 16
#define DT 10        // d tiles of 128

typedef __attribute__((ext_vector_type(8))) short short8;
typedef __attribute__((ext_vector_type(4))) float f32x4;

__device__ inline unsigned short f2bf(float f) {
    __hip_bfloat16 h = __float2bfloat16(f);
    return __builtin_bit_cast(unsigned short, h);
}
__device__ inline float fast_tanh(float x) {
    float e = __expf(2.f * x);
    return 1.f - 2.f / (e + 1.f);
}
__device__ inline short8 s8zero() {
    short8 z;
#pragma unroll
    for (int j = 0; j < 8; ++j) z[j] = 0;
    return z;
}
#define MFMA(a, b, c) __builtin_amdgcn_mfma_f32_16x16x32_bf16((a), (b), (c), 0, 0, 0)

// ---------------------------------------------------------------------------
// setup: weight cast/reorder + folded constants.
//  wcat[384][1152]: rows 0..127 = wq, 128..255 = wk, 256..383 = wv,
//  K reordered tap-major (k = tap*128 + ci).
//  hconst[co] = b_h + w_h[:,256:384].vc  (c-branch attention folds to const:
//  spatially-uniform c => uniform softmax => v_c constant).
// ---------------------------------------------------------------------------
__global__ void k_setup(const float* __restrict__ wq, const float* __restrict__ wk,
                        const float* __restrict__ wv, const float* __restrict__ wh,
                        const float* __restrict__ wo, const float* __restrict__ wx,
                        const float* __restrict__ c0, const float* __restrict__ w_vc,
                        const float* __restrict__ b_h,
                        unsigned short* __restrict__ wcat, unsigned short* __restrict__ whb,
                        unsigned short* __restrict__ wob, unsigned short* __restrict__ wxb,
                        float* __restrict__ hconst)
{
    if (blockIdx.x == 576) {
        __shared__ float vc[CH];
        int c = threadIdx.x;
        if (c < CH) {
            float s = 0.f;
            for (int ci = 0; ci < CH; ++ci) {
                const float* wp = w_vc + ((size_t)c * CH + ci) * 9;
                float ws = 0.f;
#pragma unroll
                for (int k = 0; k < 9; ++k) ws += wp[k];
                s += c0[ci] * ws;
            }
            vc[c] = s;
        }
        __syncthreads();
        if (c < CH) {
            float hs = b_h[c];
            for (int ci = 0; ci < CH; ++ci) hs += wh[(size_t)c * 384 + 256 + ci] * vc[ci];
            hconst[c] = hs;
        }
        return;
    }
    int t = blockIdx.x * 256 + threadIdx.x;    // 0..147455
    int co = t / KC;
    int rem = t - co * KC;
    int tap = rem >> 7, ci = rem & 127;
    int iidx = co * KC + ci * 9 + tap;
    wcat[t] = f2bf(wq[iidx]);
    wcat[147456 + t] = f2bf(wk[iidx]);
    wcat[294912 + t] = f2bf(wv[iidx]);
    if (t < 32768) {
        int c2 = t >> 8, k2 = t & 255;
        whb[t] = f2bf(wh[c2 * 384 + k2]);
    }
    if (t < 16384) { wob[t] = f2bf(wo[t]); wxb[t] = f2bf(wx[t]); }
}

// ---------------------------------------------------------------------------
// proj: x = w_x . inp + b_x. Wave = 16 p x 64 co, K=128; A assembled
// on-the-fly from fp32 inp. Grid (81, 2 co-groups, 8) = 1296 waves.
// ---------------------------------------------------------------------------
__global__ __launch_bounds__(64)
void k_proj(const float* __restrict__ inp, const unsigned short* __restrict__ wxb,
            const float* __restrict__ bx, unsigned short* __restrict__ xt)
{
    const int lane = threadIdx.x;
    const int quad = lane >> 4, lrow = lane & 15;
    const int p0 = blockIdx.x * 16;
    const int co0 = blockIdx.y * 64;
    const int n = blockIdx.z;
    const float* in_n = inp + (size_t)n * CH * PP;
    f32x4 acc[4] = {};

#pragma unroll
    for (int ks = 0; ks < 4; ++ks) {
        union { short8 v; unsigned short u[8]; } a;
        int ci0 = ks * 32 + quad * 8;
#pragma unroll
        for (int j = 0; j < 8; ++j)
            a.u[j] = f2bf(in_n[(size_t)(ci0 + j) * PP + p0 + lrow]);
#pragma unroll
        for (int ni = 0; ni < 4; ++ni) {
            short8 b = *(const short8*)&wxb[(size_t)(co0 + ni * 16 + lrow) * CH + ks * 32 + quad * 8];
            acc[ni] = MFMA(a.v, b, acc[ni]);
        }
    }
    unsigned short* xn = xt + (size_t)n * PP * CH;
#pragma unroll
    for (int ni = 0; ni < 4; ++ni) {
        float bv = bx[co0 + ni * 16 + lrow];
#pragma unroll
        for (int r = 0; r < 4; ++r)
            xn[(size_t)(p0 + quad * 4 + r) * CH + co0 + ni * 16 + lrow] = f2bf(acc[ni][r] + bv);
    }
}

// ---------------------------------------------------------------------------
// fused q/k/v conv. Wave = 32 tokens x 32 co. blockIdx.y in 0..11:
// y>>2: 0=q(SAME), 1=k(VALID), 2=v(VALID); co0=(y&3)*32. Grid (11,12,8).
// Inner loop: explicit register double-buffer — named prefetch registers for
// ks+1's 4 fragments force the allocator to keep loads in flight (round-6
// version compiled to 32 VGPRs and serialized every load behind vmcnt(0)).
// SAME-mode halo: clamped (always in-bounds) addresses + cndmask zeroing.
// ---------------------------------------------------------------------------
__global__ __launch_bounds__(256)
void k_conv(const unsigned short* __restrict__ xt, const unsigned short* __restrict__ wcat,
            unsigned short* __restrict__ qt, unsigned short* __restrict__ kt,
            unsigned short* __restrict__ vb)
{
    const int t = threadIdx.x;
    const int wave = t >> 6, lane = t & 63;
    const int quad = lane >> 4, lrow = lane & 15;
    const int y = blockIdx.y;
    const int mode = y >> 2;                  // 0=q(SAME), 1=k, 2=v
    const int co0 = (y & 3) * 32;
    const int n = blockIdx.z;
    const int out0 = blockIdx.x * 128 + wave * 32;
    const int limit = (mode == 0) ? PP : DD;
    if (out0 >= limit) return;
    const unsigned short* xn = xt + (size_t)n * PP * CH;

    int pr[2], pc[2];
#pragma unroll
    for (int mi = 0; mi < 2; ++mi) {
        int tok = out0 + mi * 16 + lrow; if (tok >= limit) tok = limit - 1;
        int dvs = (mode == 0) ? 36 : 34;
        pr[mi] = tok / dvs; pc[mi] = tok - pr[mi] * dvs;
    }

    auto loadA = [&](int mi, int ks) -> short8 {
        int tap = ks >> 2;
        int ky = tap / 3, kx = tap - (tap / 3) * 3;
        int ci0 = (ks & 3) * 32 + quad * 8;
        if (mode == 0) {
            int yy = pr[mi] + ky - 1, xx = pc[mi] + kx - 1;
            int yyc = yy < 0 ? 0 : (yy > 35 ? 35 : yy);
            int xxc = xx < 0 ? 0 : (xx > 35 ? 35 : xx);
            short8 v = *(const short8*)&xn[(size_t)(yyc * WWI + xxc) * CH + ci0];
            if (yy != yyc || xx != xxc) v = s8zero();
            return v;
        } else {
            return *(const short8*)&xn[(size_t)((pr[mi] + ky) * WWI + pc[mi] + kx) * CH + ci0];
        }
    };
    auto loadB = [&](int ni, int ks) -> short8 {
        return *(const short8*)&wcat[(size_t)(y * 32 + ni * 16 + lrow) * KC + ks * 32 + quad * 8];
    };

    f32x4 acc[2][2] = {};
    short8 a0 = loadA(0, 0), a1 = loadA(1, 0);
    short8 b0 = loadB(0, 0), b1 = loadB(1, 0);
#pragma unroll
    for (int ks = 0; ks < 36; ++ks) {
        short8 a0n = a0, a1n = a1, b0n = b0, b1n = b1;
        if (ks < 35) {
            a0n = loadA(0, ks + 1);
            a1n = loadA(1, ks + 1);
            b0n = loadB(0, ks + 1);
            b1n = loadB(1, ks + 1);
        }
        acc[0][0] = MFMA(a0, b0, acc[0][0]);
        acc[1][0] = MFMA(a1, b0, acc[1][0]);
        acc[0][1] = MFMA(a0, b1, acc[0][1]);
        acc[1][1] = MFMA(a1, b1, acc[1][1]);
        a0 = a0n; a1 = a1n; b0 = b0n; b1 = b1n;
    }

    if (mode == 0) {
        unsigned short* qn = qt + (size_t)n * PP * CH;
#pragma unroll
        for (int mi = 0; mi < 2; ++mi)
#pragma unroll
            for (int r = 0; r < 4; ++r) {
                int p = out0 + mi * 16 + quad * 4 + r;
                if (p < PP)
#pragma unroll
                    for (int ni = 0; ni < 2; ++ni)
                        qn[(size_t)p * CH + co0 + ni * 16 + lrow] = f2bf(acc[mi][ni][r]);
            }
    } else if (mode == 1) {
        unsigned short* kn = kt + (size_t)n * DD * CH;
#pragma unroll
        for (int mi = 0; mi < 2; ++mi)
#pragma unroll
            for (int r = 0; r < 4; ++r) {
                int d = out0 + mi * 16 + quad * 4 + r;
                if (d < DD)
#pragma unroll
                    for (int ni = 0; ni < 2; ++ni)
                        kn[(size_t)d * CH + co0 + ni * 16 + lrow] = f2bf(acc[mi][ni][r]);
            }
    } else {
        unsigned short* vn = vb + (size_t)n * CH * VP;
#pragma unroll
        for (int mi = 0; mi < 2; ++mi)
#pragma unroll
            for (int r = 0; r < 4; ++r) {
                int d = out0 + mi * 16 + quad * 4 + r;
                if (d < DD)
#pragma unroll
                    for (int ni = 0; ni < 2; ++ni)
                        vn[(size_t)(co0 + ni * 16 + lrow) * VP + d] = f2bf(acc[mi][ni][r]);
            }
    }
}

// ---------------------------------------------------------------------------
// partial attention: ONE wave per (q16-tile, d128-tile). Plain partial
// softmax (no online rescale): m,l per row + O = P.V, fp16 partials.
// Grid (81, 10, 8) = 6480 waves.
// ---------------------------------------------------------------------------
__global__ __launch_bounds__(64)
void k_attn(const unsigned short* __restrict__ qt, const unsigned short* __restrict__ kt,
            const unsigned short* __restrict__ vb, _Float16* __restrict__ po,
            float* __restrict__ pm, float* __restrict__ pl)
{
    __shared__ unsigned short lp[16 * 136];
    const int lane = threadIdx.x;
    const int quad = lane >> 4, lrow = lane & 15;
    const int qti = blockIdx.x;
    const int dt = blockIdx.y;
    const int n = blockIdx.z;
    const int q0 = qti * 16, d0 = dt * 128;
    const unsigned short* qn = qt + (size_t)n * PP * CH;
    const unsigned short* kn = kt + (size_t)n * DD * CH;
    const unsigned short* vn = vb + (size_t)n * CH * VP;

    short8 qa[4];
#pragma unroll
    for (int ks = 0; ks < 4; ++ks)
        qa[ks] = *(const short8*)&qn[(size_t)(q0 + lrow) * CH + ks * 32 + quad * 8];

    // S = Q.K^T
    f32x4 s[8] = {};
#pragma unroll
    for (int ks = 0; ks < 4; ++ks)
#pragma unroll
        for (int ni = 0; ni < 8; ++ni) {
            int d = d0 + ni * 16 + lrow; if (d >= DD) d = DD - 1;
            short8 b = *(const short8*)&kn[(size_t)d * CH + ks * 32 + quad * 8];
            s[ni] = MFMA(qa[ks], b, s[ni]);
        }
    // tail mask + row max
#pragma unroll
    for (int ni = 0; ni < 8; ++ni)
        if (d0 + ni * 16 + lrow >= DD)
#pragma unroll
            for (int r = 0; r < 4; ++r) s[ni][r] = -1e30f;

    float mx[4] = {-1e30f, -1e30f, -1e30f, -1e30f};
#pragma unroll
    for (int ni = 0; ni < 8; ++ni)
#pragma unroll
        for (int r = 0; r < 4; ++r) mx[r] = fmaxf(mx[r], s[ni][r]);
#pragma unroll
    for (int off = 1; off < 16; off <<= 1)
#pragma unroll
        for (int r = 0; r < 4; ++r) mx[r] = fmaxf(mx[r], __shfl_xor(mx[r], off, 64));

    float rs[4] = {0.f, 0.f, 0.f, 0.f};
#pragma unroll
    for (int ni = 0; ni < 8; ++ni)
#pragma unroll
        for (int r = 0; r < 4; ++r) {
            float e = __expf(s[ni][r] - mx[r]);
            s[ni][r] = e;
            rs[r] += e;
        }
#pragma unroll
    for (int off = 1; off < 16; off <<= 1)
#pragma unroll
        for (int r = 0; r < 4; ++r) rs[r] += __shfl_xor(rs[r], off, 64);

    // P -> LDS (transpose C-layout -> A-layout), single wave
#pragma unroll
    for (int ni = 0; ni < 8; ++ni)
#pragma unroll
        for (int r = 0; r < 4; ++r)
            lp[(quad * 4 + r) * 136 + ni * 16 + lrow] = f2bf(s[ni][r]);
    __syncthreads();

    // O = P.V
    f32x4 o[8] = {};
#pragma unroll
    for (int ks = 0; ks < 4; ++ks) {
        short8 pa = *(const short8*)&lp[lrow * 136 + ks * 32 + quad * 8];
#pragma unroll
        for (int ni = 0; ni < 8; ++ni) {
            short8 b = *(const short8*)&vn[(size_t)(ni * 16 + lrow) * VP + d0 + ks * 32 + quad * 8];
            o[ni] = MFMA(pa, b, o[ni]);
        }
    }

    const int base = (n * QT + qti) * DT + dt;
    _Float16* pob = po + (size_t)base * 2048;
#pragma unroll
    for (int ni = 0; ni < 8; ++ni)
#pragma unroll
        for (int r = 0; r < 4; ++r)
            pob[(quad * 4 + r) * 128 + ni * 16 + lrow] = (_Float16)o[ni][r];
    if (lrow == 0)
#pragma unroll
        for (int r = 0; r < 4; ++r) {
            pm[base * 16 + quad * 4 + r] = mx[r];
            pl[base * 16 + quad * 4 + r] = rs[r];
        }
}

// ---------------------------------------------------------------------------
// attention reduce: merge 10 d-tile partials per q16-tile. Grid (81, 8),
// 256 threads. Coalesced fp16 reads, bf16 a0t[q][c] out.
// ---------------------------------------------------------------------------
__global__ __launch_bounds__(256)
void k_ared(const _Float16* __restrict__ po, const float* __restrict__ pm,
            const float* __restrict__ pl, unsigned short* __restrict__ a0t)
{
    __shared__ float sm[160], ssc[160], smg[16], sli[16];
    const int qti = blockIdx.x;
    const int n = blockIdx.y;
    const int base = (n * QT + qti) * DT;
    const int t = threadIdx.x;
    if (t < 160) sm[t] = pm[base * 16 + t];
    __syncthreads();
    if (t < 16) {
        float mg = -1e30f;
#pragma unroll
        for (int dt = 0; dt < DT; ++dt) mg = fmaxf(mg, sm[dt * 16 + t]);
        float ls = 0.f;
#pragma unroll
        for (int dt = 0; dt < DT; ++dt) ls += __expf(sm[dt * 16 + t] - mg) * pl[base * 16 + dt * 16 + t];
        smg[t] = mg; sli[t] = 1.f / ls;
    }
    __syncthreads();
    if (t < 160) ssc[t] = __expf(sm[t] - smg[t & 15]);
    __syncthreads();

    unsigned short* an = a0t + (size_t)n * PP * CH;
#pragma unroll
    for (int k = 0; k < 8; ++k) {
        int idx = t + k * 256;
        int row = idx >> 7, c = idx & 127;
        float acc = 0.f;
#pragma unroll
        for (int dt = 0; dt < DT; ++dt)
            acc += ssc[dt * 16 + row] * (float)po[(size_t)(base + dt) * 2048 + idx];
        an[(size_t)(qti * 16 + row) * CH + c] = f2bf(acc * sli[row]);
    }
}

// ---------------------------------------------------------------------------
// fused h+out: 4 waves per 16-p tile. Wave w: GEMM1 co-slice {2w,2w+1}x16 of
// h=tanh(whb.[xt;a0t]+hconst) -> lh -> barrier -> GEMM2 co-slice of
// out = wob.h + b_o (fp32). Grid (81, 8) = 2592 waves.
// ---------------------------------------------------------------------------
__global__ __launch_bounds__(256)
void k_hout(const unsigned short* __restrict__ xt, const unsigned short* __restrict__ a0t,
            const unsigned short* __restrict__ whb, const float* __restrict__ hconst,
            const unsigned short* __restrict__ wob, const float* __restrict__ bo,
            float* __restrict__ out)
{
    __shared__ unsigned short lh[16 * 136];
    const int t = threadIdx.x;
    const int wave = t >> 6, lane = t & 63;
    const int quad = lane >> 4, lrow = lane & 15;
    const int p0 = blockIdx.x * 16;
    const int n = blockIdx.y;
    const unsigned short* x0 = xt + (size_t)n * PP * CH;
    const unsigned short* a0 = a0t + (size_t)n * PP * CH;

    f32x4 acc[2] = {};
#pragma unroll
    for (int ks = 0; ks < 8; ++ks) {
        int col = (ks & 3) * 32 + quad * 8;
        const unsigned short* src = (ks < 4) ? x0 : a0;
        short8 a = *(const short8*)&src[(size_t)(p0 + lrow) * CH + col];
#pragma unroll
        for (int j = 0; j < 2; ++j) {
            int ni = wave * 2 + j;
            short8 b = *(const short8*)&whb[(size_t)(ni * 16 + lrow) * 256 + ks * 32 + quad * 8];
            acc[j] = MFMA(a, b, acc[j]);
        }
    }
#pragma unroll
    for (int j = 0; j < 2; ++j) {
        int ni = wave * 2 + j;
        float hc = hconst[ni * 16 + lrow];
#pragma unroll
        for (int r = 0; r < 4; ++r)
            lh[(quad * 4 + r) * 136 + ni * 16 + lrow] = f2bf(fast_tanh(acc[j][r] + hc));
    }
    __syncthreads();

    f32x4 acc2[2] = {};
#pragma unroll
    for (int ks = 0; ks < 4; ++ks) {
        short8 a = *(const short8*)&lh[lrow * 136 + ks * 32 + quad * 8];
#pragma unroll
        for (int j = 0; j < 2; ++j) {
            int ni = wave * 2 + j;
            short8 b = *(const short8*)&wob[(size_t)(ni * 16 + lrow) * CH + ks * 32 + quad * 8];
            acc2[j] = MFMA(a, b, acc2[j]);
        }
    }
#pragma unroll
    for (int j = 0; j < 2; ++j) {
        int ni = wave * 2 + j;
        float bv = bo[ni * 16 + lrow];
#pragma unroll
        for (int r = 0; r < 4; ++r)
            out[((size_t)(n * CH + ni * 16 + lrow)) * PP + p0 + quad * 4 + r] = acc2[j][r] + bv;
    }
}

// ---------------------------------------------------------------------------
extern "C" void kernel_launch(void* const* d_in, const int* in_sizes, int n_in,
                              void* d_out, int out_size, void* d_ws, size_t ws_size,
                              hipStream_t stream)
{
    const float* inp  = (const float*)d_in[0];
    const float* c0   = (const float*)d_in[1];
    const float* w_x  = (const float*)d_in[2];
    const float* b_x  = (const float*)d_in[3];
    const float* w_qx = (const float*)d_in[4];
    const float* w_kx = (const float*)d_in[6];
    const float* w_vx = (const float*)d_in[8];
    const float* w_vc = (const float*)d_in[9];
    const float* w_h  = (const float*)d_in[14];
    const float* b_h  = (const float*)d_in[15];
    const float* w_o  = (const float*)d_in[16];
    const float* b_o  = (const float*)d_in[17];
    float* out = (float*)d_out;

    char* w = (char*)d_ws;
    unsigned short* xt   = (unsigned short*)(w);             // 2,654,208
    unsigned short* qt   = (unsigned short*)(w + 2654208);   // 2,654,208
    unsigned short* kt   = (unsigned short*)(w + 5308416);   // 2,367,488
    unsigned short* vb   = (unsigned short*)(w + 7675904);   // 2,621,440
    unsigned short* a0t  = (unsigned short*)(w + 10297344);  // 2,654,208
    unsigned short* wcat = (unsigned short*)(w + 12951552);  // 884,736
    unsigned short* wxb  = (unsigned short*)(w + 13836288);  // 32,768
    unsigned short* whb  = (unsigned short*)(w + 13869056);  // 65,536
    unsigned short* wob  = (unsigned short*)(w + 13934592);  // 32,768
    float* hconst        = (float*)(w + 13967360);           // 512
    float* pm            = (float*)(w + 13967872);           // 414,720
    float* pl            = (float*)(w + 14382592);           // 414,720
    _Float16* po         = (_Float16*)(w + 14797312);        // 26,542,080 -> 41.3 MB total

    hipLaunchKernelGGL(k_setup, dim3(577), dim3(256), 0, stream,
                       w_qx, w_kx, w_vx, w_h, w_o, w_x, c0, w_vc, b_h,
                       wcat, whb, wob, wxb, hconst);

    hipLaunchKernelGGL(k_proj, dim3(QT, 2, NN), dim3(64), 0, stream, inp, wxb, b_x, xt);

    hipLaunchKernelGGL(k_conv, dim3(11, 12, NN), dim3(256), 0, stream, xt, wcat, qt, kt, vb);

    hipLaunchKernelGGL(k_attn, dim3(QT, DT, NN), dim3(64), 0, stream, qt, kt, vb, po, pm, pl);
    hipLaunchKernelGGL(k_ared, dim3(QT, NN), dim3(256), 0, stream, po, pm, pl, a0t);

    hipLaunchKernelGGL(k_hout, dim3(QT, NN), dim3(256), 0, stream,
                       xt, a0t, whb, hconst, wob, b_o, out);
}

// Round 11
// 240.105 us; speedup vs baseline: 1.4241x; 1.2284x over previous
//
#include <hip/hip_runtime.h>
#include <hip/hip_bf16.h>
#include <math.h>

#define NN 8
#define CH 128
#define HH 36
#define WWI 36
#define PP 1296      // 36*36
#define DD 1156      // 34*34
#define VP 1280      // vb row pitch (shorts) — covers d-tail fragment reads
#define KC 1152      // 128*9
#define QT 81        // q tiles of 16
#define DT 10        // d tiles of 128

typedef __attribute__((ext_vector_type(8))) short short8;
typedef __attribute__((ext_vector_type(4))) float f32x4;

__device__ inline unsigned short f2bf(float f) {
    __hip_bfloat16 h = __float2bfloat16(f);
    return __builtin_bit_cast(unsigned short, h);
}
__device__ inline float fast_tanh(float x) {
    float e = __expf(2.f * x);
    return 1.f - 2.f / (e + 1.f);
}
#define MFMA(a, b, c) __builtin_amdgcn_mfma_f32_16x16x32_bf16((a), (b), (c), 0, 0, 0)

// ---------------------------------------------------------------------------
// setup: weight cast/reorder + folded constants (identical to round 9).
// wcat[384][1152]: 0..127=wq, 128..255=wk, 256..383=wv, K tap-major.
// hconst = b_h + w_h[:,256:384].vc (c-branch attention folds to a constant:
// spatially-uniform c => uniform softmax => constant v_c).
// ---------------------------------------------------------------------------
__global__ void k_setup(const float* __restrict__ wq, const float* __restrict__ wk,
                        const float* __restrict__ wv, const float* __restrict__ wh,
                        const float* __restrict__ wo, const float* __restrict__ wx,
                        const float* __restrict__ c0, const float* __restrict__ w_vc,
                        const float* __restrict__ b_h,
                        unsigned short* __restrict__ wcat, unsigned short* __restrict__ whb,
                        unsigned short* __restrict__ wob, unsigned short* __restrict__ wxb,
                        float* __restrict__ hconst)
{
    if (blockIdx.x == 576) {
        __shared__ float vc[CH];
        int c = threadIdx.x;
        if (c < CH) {
            float s = 0.f;
            for (int ci = 0; ci < CH; ++ci) {
                const float* wp = w_vc + ((size_t)c * CH + ci) * 9;
                float ws = 0.f;
#pragma unroll
                for (int k = 0; k < 9; ++k) ws += wp[k];
                s += c0[ci] * ws;
            }
            vc[c] = s;
        }
        __syncthreads();
        if (c < CH) {
            float hs = b_h[c];
            for (int ci = 0; ci < CH; ++ci) hs += wh[(size_t)c * 384 + 256 + ci] * vc[ci];
            hconst[c] = hs;
        }
        return;
    }
    int t = blockIdx.x * 256 + threadIdx.x;    // 0..147455
    int co = t / KC;
    int rem = t - co * KC;
    int tap = rem >> 7, ci = rem & 127;
    int iidx = co * KC + ci * 9 + tap;
    wcat[t] = f2bf(wq[iidx]);
    wcat[147456 + t] = f2bf(wk[iidx]);
    wcat[294912 + t] = f2bf(wv[iidx]);
    if (t < 32768) {
        int c2 = t >> 8, k2 = t & 255;
        whb[t] = f2bf(wh[c2 * 384 + k2]);
    }
    if (t < 16384) { wob[t] = f2bf(wo[t]); wxb[t] = f2bf(wx[t]); }
}

// ---------------------------------------------------------------------------
// proj: x = w_x . inp + b_x. Wave = 16 p x 64 co, K=128; A assembled
// on-the-fly from fp32 inp. Grid (81, 2 co-groups, 8) = 1296 waves.
// (identical to round 9)
// ---------------------------------------------------------------------------
__global__ __launch_bounds__(64)
void k_proj(const float* __restrict__ inp, const unsigned short* __restrict__ wxb,
            const float* __restrict__ bx, unsigned short* __restrict__ xt)
{
    const int lane = threadIdx.x;
    const int quad = lane >> 4, lrow = lane & 15;
    const int p0 = blockIdx.x * 16;
    const int co0 = blockIdx.y * 64;
    const int n = blockIdx.z;
    const float* in_n = inp + (size_t)n * CH * PP;
    f32x4 acc[4] = {};

#pragma unroll
    for (int ks = 0; ks < 4; ++ks) {
        union { short8 v; unsigned short u[8]; } a;
        int ci0 = ks * 32 + quad * 8;
#pragma unroll
        for (int j = 0; j < 8; ++j)
            a.u[j] = f2bf(in_n[(size_t)(ci0 + j) * PP + p0 + lrow]);
#pragma unroll
        for (int ni = 0; ni < 4; ++ni) {
            short8 b = *(const short8*)&wxb[(size_t)(co0 + ni * 16 + lrow) * CH + ks * 32 + quad * 8];
            acc[ni] = MFMA(a.v, b, acc[ni]);
        }
    }
    unsigned short* xn = xt + (size_t)n * PP * CH;
#pragma unroll
    for (int ni = 0; ni < 4; ++ni) {
        float bv = bx[co0 + ni * 16 + lrow];
#pragma unroll
        for (int r = 0; r < 4; ++r)
            xn[(size_t)(p0 + quad * 4 + r) * CH + co0 + ni * 16 + lrow] = f2bf(acc[ni][r] + bv);
    }
}

// ---------------------------------------------------------------------------
// fused q/k/v conv, LDS-staged (round-2/3-proven pattern), double-buffered.
// Block = 4 waves, tile 64 tokens x 128 co, K=1152 in 36 chunks of 32.
// Per chunk, per thread: 3 independent uint4 global loads for chunk ks+1
// issued BEFORE compute of chunk ks (latency overlapped structurally), then
// ds_write_b128 x3 (vmcnt wait lands here), one barrier.
// Per chunk, per wave: 4 A + 2 B ds_read_b128 (pitch 40 -> free 2-way) +
// 8 MFMA. Wave w owns co groups {2w, 2w+1} x all 64 tokens.
// Grid (21, 3 modes, 8); modes: 0=q(SAME), 1=k(VALID), 2=v(VALID).
// ---------------------------------------------------------------------------
__global__ __launch_bounds__(256)
void k_conv(const unsigned short* __restrict__ xt, const unsigned short* __restrict__ wcat,
            unsigned short* __restrict__ qt, unsigned short* __restrict__ kt,
            unsigned short* __restrict__ vb)
{
    __shared__ unsigned short lA[2][64 * 40];     // 2 x 5120 B
    __shared__ unsigned short lB[2][128 * 40];    // 2 x 10240 B
    const int t = threadIdx.x;
    const int wave = t >> 6, lane = t & 63;
    const int quad = lane >> 4, lrow = lane & 15;
    const int mode = blockIdx.y;
    const int n = blockIdx.z;
    const int limit = (mode == 0) ? PP : DD;
    const int tile0 = blockIdx.x * 64;
    if (tile0 >= limit) return;                   // whole block uniform exit
    const unsigned short* xn = xt + (size_t)n * PP * CH;
    const unsigned short* wb = wcat + (size_t)mode * 128 * KC;

    // staging roles: A row = t>>2 (64 token rows), seg = t&3 (4 x 8 shorts);
    // B rows = t>>2 and (t>>2)+64.
    const int arow = t >> 2, aseg = t & 3;
    int apr, apc;
    {
        int tok = tile0 + arow; if (tok >= limit) tok = limit - 1;
        int dv = (mode == 0) ? 36 : 34;
        apr = tok / dv; apc = tok - apr * dv;
    }

    uint4 ra, rb0, rb1;
    auto loadChunk = [&](int ks) {
        int tap = ks >> 2;
        int ky = tap / 3, kx = tap - ky * 3;
        int ci = (ks & 3) * 32 + aseg * 8;
        if (mode == 0) {
            int yy = apr + ky - 1, xx = apc + kx - 1;
            bool ok = (yy >= 0) && (yy < HH) && (xx >= 0) && (xx < WWI);
            ra = make_uint4(0, 0, 0, 0);
            if (ok) ra = *(const uint4*)&xn[(size_t)(yy * WWI + xx) * CH + ci];
        } else {
            int yy = apr + ky, xx = apc + kx;
            ra = *(const uint4*)&xn[(size_t)(yy * WWI + xx) * CH + ci];
        }
        rb0 = *(const uint4*)&wb[(size_t)arow * KC + ks * 32 + aseg * 8];
        rb1 = *(const uint4*)&wb[(size_t)(arow + 64) * KC + ks * 32 + aseg * 8];
    };
    auto storeChunk = [&](int buf) {
        *(uint4*)&lA[buf][arow * 40 + aseg * 8] = ra;
        *(uint4*)&lB[buf][arow * 40 + aseg * 8] = rb0;
        *(uint4*)&lB[buf][(arow + 64) * 40 + aseg * 8] = rb1;
    };

    f32x4 acc[4][2] = {};
    loadChunk(0);
    storeChunk(0);
    __syncthreads();

#pragma unroll
    for (int ks = 0; ks < 36; ++ks) {
        const int buf = ks & 1;
        if (ks < 35) loadChunk(ks + 1);          // in flight during compute
        short8 b0 = *(const short8*)&lB[buf][((wave * 2) * 16 + lrow) * 40 + quad * 8];
        short8 b1 = *(const short8*)&lB[buf][((wave * 2 + 1) * 16 + lrow) * 40 + quad * 8];
#pragma unroll
        for (int mi = 0; mi < 4; ++mi) {
            short8 a = *(const short8*)&lA[buf][(mi * 16 + lrow) * 40 + quad * 8];
            acc[mi][0] = MFMA(a, b0, acc[mi][0]);
            acc[mi][1] = MFMA(a, b1, acc[mi][1]);
        }
        if (ks < 35) storeChunk(buf ^ 1);        // vmcnt wait lands here
        __syncthreads();
    }

    if (mode == 0) {
        unsigned short* qn = qt + (size_t)n * PP * CH;
#pragma unroll
        for (int mi = 0; mi < 4; ++mi)
#pragma unroll
            for (int r = 0; r < 4; ++r) {
                int p = tile0 + mi * 16 + quad * 4 + r;
                if (p < PP)
#pragma unroll
                    for (int ni = 0; ni < 2; ++ni)
                        qn[(size_t)p * CH + (wave * 2 + ni) * 16 + lrow] = f2bf(acc[mi][ni][r]);
            }
    } else if (mode == 1) {
        unsigned short* kn = kt + (size_t)n * DD * CH;
#pragma unroll
        for (int mi = 0; mi < 4; ++mi)
#pragma unroll
            for (int r = 0; r < 4; ++r) {
                int d = tile0 + mi * 16 + quad * 4 + r;
                if (d < DD)
#pragma unroll
                    for (int ni = 0; ni < 2; ++ni)
                        kn[(size_t)d * CH + (wave * 2 + ni) * 16 + lrow] = f2bf(acc[mi][ni][r]);
            }
    } else {
        unsigned short* vn = vb + (size_t)n * CH * VP;
#pragma unroll
        for (int mi = 0; mi < 4; ++mi)
#pragma unroll
            for (int r = 0; r < 4; ++r) {
                int d = tile0 + mi * 16 + quad * 4 + r;
                if (d < DD)
#pragma unroll
                    for (int ni = 0; ni < 2; ++ni)
                        vn[(size_t)((wave * 2 + ni) * 16 + lrow) * VP + d] = f2bf(acc[mi][ni][r]);
            }
    }
}

// ---------------------------------------------------------------------------
// partial attention: ONE wave per (q16-tile, d128-tile) — identical round 9.
// ---------------------------------------------------------------------------
__global__ __launch_bounds__(64)
void k_attn(const unsigned short* __restrict__ qt, const unsigned short* __restrict__ kt,
            const unsigned short* __restrict__ vb, _Float16* __restrict__ po,
            float* __restrict__ pm, float* __restrict__ pl)
{
    __shared__ unsigned short lp[16 * 136];
    const int lane = threadIdx.x;
    const int quad = lane >> 4, lrow = lane & 15;
    const int qti = blockIdx.x;
    const int dt = blockIdx.y;
    const int n = blockIdx.z;
    const int q0 = qti * 16, d0 = dt * 128;
    const unsigned short* qn = qt + (size_t)n * PP * CH;
    const unsigned short* kn = kt + (size_t)n * DD * CH;
    const unsigned short* vn = vb + (size_t)n * CH * VP;

    short8 qa[4];
#pragma unroll
    for (int ks = 0; ks < 4; ++ks)
        qa[ks] = *(const short8*)&qn[(size_t)(q0 + lrow) * CH + ks * 32 + quad * 8];

    f32x4 s[8] = {};
#pragma unroll
    for (int ks = 0; ks < 4; ++ks)
#pragma unroll
        for (int ni = 0; ni < 8; ++ni) {
            int d = d0 + ni * 16 + lrow; if (d >= DD) d = DD - 1;
            short8 b = *(const short8*)&kn[(size_t)d * CH + ks * 32 + quad * 8];
            s[ni] = MFMA(qa[ks], b, s[ni]);
        }
#pragma unroll
    for (int ni = 0; ni < 8; ++ni)
        if (d0 + ni * 16 + lrow >= DD)
#pragma unroll
            for (int r = 0; r < 4; ++r) s[ni][r] = -1e30f;

    float mx[4] = {-1e30f, -1e30f, -1e30f, -1e30f};
#pragma unroll
    for (int ni = 0; ni < 8; ++ni)
#pragma unroll
        for (int r = 0; r < 4; ++r) mx[r] = fmaxf(mx[r], s[ni][r]);
#pragma unroll
    for (int off = 1; off < 16; off <<= 1)
#pragma unroll
        for (int r = 0; r < 4; ++r) mx[r] = fmaxf(mx[r], __shfl_xor(mx[r], off, 64));

    float rs[4] = {0.f, 0.f, 0.f, 0.f};
#pragma unroll
    for (int ni = 0; ni < 8; ++ni)
#pragma unroll
        for (int r = 0; r < 4; ++r) {
            float e = __expf(s[ni][r] - mx[r]);
            s[ni][r] = e;
            rs[r] += e;
        }
#pragma unroll
    for (int off = 1; off < 16; off <<= 1)
#pragma unroll
        for (int r = 0; r < 4; ++r) rs[r] += __shfl_xor(rs[r], off, 64);

#pragma unroll
    for (int ni = 0; ni < 8; ++ni)
#pragma unroll
        for (int r = 0; r < 4; ++r)
            lp[(quad * 4 + r) * 136 + ni * 16 + lrow] = f2bf(s[ni][r]);
    __syncthreads();

    f32x4 o[8] = {};
#pragma unroll
    for (int ks = 0; ks < 4; ++ks) {
        short8 pa = *(const short8*)&lp[lrow * 136 + ks * 32 + quad * 8];
#pragma unroll
        for (int ni = 0; ni < 8; ++ni) {
            short8 b = *(const short8*)&vn[(size_t)(ni * 16 + lrow) * VP + d0 + ks * 32 + quad * 8];
            o[ni] = MFMA(pa, b, o[ni]);
        }
    }

    const int base = (n * QT + qti) * DT + dt;
    _Float16* pob = po + (size_t)base * 2048;
#pragma unroll
    for (int ni = 0; ni < 8; ++ni)
#pragma unroll
        for (int r = 0; r < 4; ++r)
            pob[(quad * 4 + r) * 128 + ni * 16 + lrow] = (_Float16)o[ni][r];
    if (lrow == 0)
#pragma unroll
        for (int r = 0; r < 4; ++r) {
            pm[base * 16 + quad * 4 + r] = mx[r];
            pl[base * 16 + quad * 4 + r] = rs[r];
        }
}

// ---------------------------------------------------------------------------
// attention reduce — identical round 9.
// ---------------------------------------------------------------------------
__global__ __launch_bounds__(256)
void k_ared(const _Float16* __restrict__ po, const float* __restrict__ pm,
            const float* __restrict__ pl, unsigned short* __restrict__ a0t)
{
    __shared__ float sm[160], ssc[160], smg[16], sli[16];
    const int qti = blockIdx.x;
    const int n = blockIdx.y;
    const int base = (n * QT + qti) * DT;
    const int t = threadIdx.x;
    if (t < 160) sm[t] = pm[base * 16 + t];
    __syncthreads();
    if (t < 16) {
        float mg = -1e30f;
#pragma unroll
        for (int dt = 0; dt < DT; ++dt) mg = fmaxf(mg, sm[dt * 16 + t]);
        float ls = 0.f;
#pragma unroll
        for (int dt = 0; dt < DT; ++dt) ls += __expf(sm[dt * 16 + t] - mg) * pl[base * 16 + dt * 16 + t];
        smg[t] = mg; sli[t] = 1.f / ls;
    }
    __syncthreads();
    if (t < 160) ssc[t] = __expf(sm[t] - smg[t & 15]);
    __syncthreads();

    unsigned short* an = a0t + (size_t)n * PP * CH;
#pragma unroll
    for (int k = 0; k < 8; ++k) {
        int idx = t + k * 256;
        int row = idx >> 7, c = idx & 127;
        float acc = 0.f;
#pragma unroll
        for (int dt = 0; dt < DT; ++dt)
            acc += ssc[dt * 16 + row] * (float)po[(size_t)(base + dt) * 2048 + idx];
        an[(size_t)(qti * 16 + row) * CH + c] = f2bf(acc * sli[row]);
    }
}

// ---------------------------------------------------------------------------
// fused h+out — identical round 9.
// ---------------------------------------------------------------------------
__global__ __launch_bounds__(256)
void k_hout(const unsigned short* __restrict__ xt, const unsigned short* __restrict__ a0t,
            const unsigned short* __restrict__ whb, const float* __restrict__ hconst,
            const unsigned short* __restrict__ wob, const float* __restrict__ bo,
            float* __restrict__ out)
{
    __shared__ unsigned short lh[16 * 136];
    const int t = threadIdx.x;
    const int wave = t >> 6, lane = t & 63;
    const int quad = lane >> 4, lrow = lane & 15;
    const int p0 = blockIdx.x * 16;
    const int n = blockIdx.y;
    const unsigned short* x0 = xt + (size_t)n * PP * CH;
    const unsigned short* a0 = a0t + (size_t)n * PP * CH;

    f32x4 acc[2] = {};
#pragma unroll
    for (int ks = 0; ks < 8; ++ks) {
        int col = (ks & 3) * 32 + quad * 8;
        const unsigned short* src = (ks < 4) ? x0 : a0;
        short8 a = *(const short8*)&src[(size_t)(p0 + lrow) * CH + col];
#pragma unroll
        for (int j = 0; j < 2; ++j) {
            int ni = wave * 2 + j;
            short8 b = *(const short8*)&whb[(size_t)(ni * 16 + lrow) * 256 + ks * 32 + quad * 8];
            acc[j] = MFMA(a, b, acc[j]);
        }
    }
#pragma unroll
    for (int j = 0; j < 2; ++j) {
        int ni = wave * 2 + j;
        float hc = hconst[ni * 16 + lrow];
#pragma unroll
        for (int r = 0; r < 4; ++r)
            lh[(quad * 4 + r) * 136 + ni * 16 + lrow] = f2bf(fast_tanh(acc[j][r] + hc));
    }
    __syncthreads();

    f32x4 acc2[2] = {};
#pragma unroll
    for (int ks = 0; ks < 4; ++ks) {
        short8 a = *(const short8*)&lh[lrow * 136 + ks * 32 + quad * 8];
#pragma unroll
        for (int j = 0; j < 2; ++j) {
            int ni = wave * 2 + j;
            short8 b = *(const short8*)&wob[(size_t)(ni * 16 + lrow) * CH + ks * 32 + quad * 8];
            acc2[j] = MFMA(a, b, acc2[j]);
        }
    }
#pragma unroll
    for (int j = 0; j < 2; ++j) {
        int ni = wave * 2 + j;
        float bv = bo[ni * 16 + lrow];
#pragma unroll
        for (int r = 0; r < 4; ++r)
            out[((size_t)(n * CH + ni * 16 + lrow)) * PP + p0 + quad * 4 + r] = acc2[j][r] + bv;
    }
}

// ---------------------------------------------------------------------------
extern "C" void kernel_launch(void* const* d_in, const int* in_sizes, int n_in,
                              void* d_out, int out_size, void* d_ws, size_t ws_size,
                              hipStream_t stream)
{
    const float* inp  = (const float*)d_in[0];
    const float* c0   = (const float*)d_in[1];
    const float* w_x  = (const float*)d_in[2];
    const float* b_x  = (const float*)d_in[3];
    const float* w_qx = (const float*)d_in[4];
    const float* w_kx = (const float*)d_in[6];
    const float* w_vx = (const float*)d_in[8];
    const float* w_vc = (const float*)d_in[9];
    const float* w_h  = (const float*)d_in[14];
    const float* b_h  = (const float*)d_in[15];
    const float* w_o  = (const float*)d_in[16];
    const float* b_o  = (const float*)d_in[17];
    float* out = (float*)d_out;

    char* w = (char*)d_ws;
    unsigned short* xt   = (unsigned short*)(w);             // 2,654,208
    unsigned short* qt   = (unsigned short*)(w + 2654208);   // 2,654,208
    unsigned short* kt   = (unsigned short*)(w + 5308416);   // 2,367,488
    unsigned short* vb   = (unsigned short*)(w + 7675904);   // 2,621,440
    unsigned short* a0t  = (unsigned short*)(w + 10297344);  // 2,654,208
    unsigned short* wcat = (unsigned short*)(w + 12951552);  // 884,736
    unsigned short* wxb  = (unsigned short*)(w + 13836288);  // 32,768
    unsigned short* whb  = (unsigned short*)(w + 13869056);  // 65,536
    unsigned short* wob  = (unsigned short*)(w + 13934592);  // 32,768
    float* hconst        = (float*)(w + 13967360);           // 512
    float* pm            = (float*)(w + 13967872);           // 414,720
    float* pl            = (float*)(w + 14382592);           // 414,720
    _Float16* po         = (_Float16*)(w + 14797312);        // 26,542,080 -> 41.3 MB total

    hipLaunchKernelGGL(k_setup, dim3(577), dim3(256), 0, stream,
                       w_qx, w_kx, w_vx, w_h, w_o, w_x, c0, w_vc, b_h,
                       wcat, whb, wob, wxb, hconst);

    hipLaunchKernelGGL(k_proj, dim3(QT, 2, NN), dim3(64), 0, stream, inp, wxb, b_x, xt);

    hipLaunchKernelGGL(k_conv, dim3(21, 3, NN), dim3(256), 0, stream, xt, wcat, qt, kt, vb);

    hipLaunchKernelGGL(k_attn, dim3(QT, DT, NN), dim3(64), 0, stream, qt, kt, vb, po, pm, pl);
    hipLaunchKernelGGL(k_ared, dim3(QT, NN), dim3(256), 0, stream, po, pm, pl, a0t);

    hipLaunchKernelGGL(k_hout, dim3(QT, NN), dim3(256), 0, stream,
                       xt, a0t, whb, hconst, wob, b_o, out);
}

// Round 13
// 203.510 us; speedup vs baseline: 1.6801x; 1.1798x over previous
//
#include <hip/hip_runtime.h>
#include <hip/hip_bf16.h>
#include <math.h>

#define NN 8
#define CH 128
#define HH 36
#define WWI 36
#define PP 1296      // 36*36
#define DD 1156      // 34*34
#define VP 1280      // vb row pitch (shorts) — covers d-tail fragment reads
#define KC 1152      // 128*9
#define QT 81        // q tiles of 16
#define DT 10        // d tiles of 128

typedef __attribute__((ext_vector_type(8))) short short8;
typedef __attribute__((ext_vector_type(4))) float f32x4;

__device__ inline unsigned short f2bf(float f) {
    __hip_bfloat16 h = __float2bfloat16(f);
    return __builtin_bit_cast(unsigned short, h);
}
__device__ inline float fast_tanh(float x) {
    float e = __expf(2.f * x);
    return 1.f - 2.f / (e + 1.f);
}
#define MFMA(a, b, c) __builtin_amdgcn_mfma_f32_16x16x32_bf16((a), (b), (c), 0, 0, 0)

// ---------------------------------------------------------------------------
// setup: weight cast/reorder + folded constants (identical to round 11).
// ---------------------------------------------------------------------------
__global__ void k_setup(const float* __restrict__ wq, const float* __restrict__ wk,
                        const float* __restrict__ wv, const float* __restrict__ wh,
                        const float* __restrict__ wo, const float* __restrict__ wx,
                        const float* __restrict__ c0, const float* __restrict__ w_vc,
                        const float* __restrict__ b_h,
                        unsigned short* __restrict__ wcat, unsigned short* __restrict__ whb,
                        unsigned short* __restrict__ wob, unsigned short* __restrict__ wxb,
                        float* __restrict__ hconst)
{
    if (blockIdx.x == 576) {
        __shared__ float vc[CH];
        int c = threadIdx.x;
        if (c < CH) {
            float s = 0.f;
            for (int ci = 0; ci < CH; ++ci) {
                const float* wp = w_vc + ((size_t)c * CH + ci) * 9;
                float ws = 0.f;
#pragma unroll
                for (int k = 0; k < 9; ++k) ws += wp[k];
                s += c0[ci] * ws;
            }
            vc[c] = s;
        }
        __syncthreads();
        if (c < CH) {
            float hs = b_h[c];
            for (int ci = 0; ci < CH; ++ci) hs += wh[(size_t)c * 384 + 256 + ci] * vc[ci];
            hconst[c] = hs;
        }
        return;
    }
    int t = blockIdx.x * 256 + threadIdx.x;    // 0..147455
    int co = t / KC;
    int rem = t - co * KC;
    int tap = rem >> 7, ci = rem & 127;
    int iidx = co * KC + ci * 9 + tap;
    wcat[t] = f2bf(wq[iidx]);
    wcat[147456 + t] = f2bf(wk[iidx]);
    wcat[294912 + t] = f2bf(wv[iidx]);
    if (t < 32768) {
        int c2 = t >> 8, k2 = t & 255;
        whb[t] = f2bf(wh[c2 * 384 + k2]);
    }
    if (t < 16384) { wob[t] = f2bf(wo[t]); wxb[t] = f2bf(wx[t]); }
}

// ---------------------------------------------------------------------------
// proj — identical to round 11.
// ---------------------------------------------------------------------------
__global__ __launch_bounds__(64)
void k_proj(const float* __restrict__ inp, const unsigned short* __restrict__ wxb,
            const float* __restrict__ bx, unsigned short* __restrict__ xt)
{
    const int lane = threadIdx.x;
    const int quad = lane >> 4, lrow = lane & 15;
    const int p0 = blockIdx.x * 16;
    const int co0 = blockIdx.y * 64;
    const int n = blockIdx.z;
    const float* in_n = inp + (size_t)n * CH * PP;
    f32x4 acc[4] = {};

#pragma unroll
    for (int ks = 0; ks < 4; ++ks) {
        union { short8 v; unsigned short u[8]; } a;
        int ci0 = ks * 32 + quad * 8;
#pragma unroll
        for (int j = 0; j < 8; ++j)
            a.u[j] = f2bf(in_n[(size_t)(ci0 + j) * PP + p0 + lrow]);
#pragma unroll
        for (int ni = 0; ni < 4; ++ni) {
            short8 b = *(const short8*)&wxb[(size_t)(co0 + ni * 16 + lrow) * CH + ks * 32 + quad * 8];
            acc[ni] = MFMA(a.v, b, acc[ni]);
        }
    }
    unsigned short* xn = xt + (size_t)n * PP * CH;
#pragma unroll
    for (int ni = 0; ni < 4; ++ni) {
        float bv = bx[co0 + ni * 16 + lrow];
#pragma unroll
        for (int r = 0; r < 4; ++r)
            xn[(size_t)(p0 + quad * 4 + r) * CH + co0 + ni * 16 + lrow] = f2bf(acc[ni][r] + bv);
    }
}

// ---------------------------------------------------------------------------
// fused q/k/v conv — identical to round 11 (LDS-staged, double-buffered).
// ---------------------------------------------------------------------------
__global__ __launch_bounds__(256)
void k_conv(const unsigned short* __restrict__ xt, const unsigned short* __restrict__ wcat,
            unsigned short* __restrict__ qt, unsigned short* __restrict__ kt,
            unsigned short* __restrict__ vb)
{
    __shared__ unsigned short lA[2][64 * 40];     // 2 x 5120 B
    __shared__ unsigned short lB[2][128 * 40];    // 2 x 10240 B
    const int t = threadIdx.x;
    const int wave = t >> 6, lane = t & 63;
    const int quad = lane >> 4, lrow = lane & 15;
    const int mode = blockIdx.y;
    const int n = blockIdx.z;
    const int limit = (mode == 0) ? PP : DD;
    const int tile0 = blockIdx.x * 64;
    if (tile0 >= limit) return;
    const unsigned short* xn = xt + (size_t)n * PP * CH;
    const unsigned short* wb = wcat + (size_t)mode * 128 * KC;

    const int arow = t >> 2, aseg = t & 3;
    int apr, apc;
    {
        int tok = tile0 + arow; if (tok >= limit) tok = limit - 1;
        int dv = (mode == 0) ? 36 : 34;
        apr = tok / dv; apc = tok - apr * dv;
    }

    uint4 ra, rb0, rb1;
    auto loadChunk = [&](int ks) {
        int tap = ks >> 2;
        int ky = tap / 3, kx = tap - ky * 3;
        int ci = (ks & 3) * 32 + aseg * 8;
        if (mode == 0) {
            int yy = apr + ky - 1, xx = apc + kx - 1;
            bool ok = (yy >= 0) && (yy < HH) && (xx >= 0) && (xx < WWI);
            ra = make_uint4(0, 0, 0, 0);
            if (ok) ra = *(const uint4*)&xn[(size_t)(yy * WWI + xx) * CH + ci];
        } else {
            int yy = apr + ky, xx = apc + kx;
            ra = *(const uint4*)&xn[(size_t)(yy * WWI + xx) * CH + ci];
        }
        rb0 = *(const uint4*)&wb[(size_t)arow * KC + ks * 32 + aseg * 8];
        rb1 = *(const uint4*)&wb[(size_t)(arow + 64) * KC + ks * 32 + aseg * 8];
    };
    auto storeChunk = [&](int buf) {
        *(uint4*)&lA[buf][arow * 40 + aseg * 8] = ra;
        *(uint4*)&lB[buf][arow * 40 + aseg * 8] = rb0;
        *(uint4*)&lB[buf][(arow + 64) * 40 + aseg * 8] = rb1;
    };

    f32x4 acc[4][2] = {};
    loadChunk(0);
    storeChunk(0);
    __syncthreads();

#pragma unroll
    for (int ks = 0; ks < 36; ++ks) {
        const int buf = ks & 1;
        if (ks < 35) loadChunk(ks + 1);
        short8 b0 = *(const short8*)&lB[buf][((wave * 2) * 16 + lrow) * 40 + quad * 8];
        short8 b1 = *(const short8*)&lB[buf][((wave * 2 + 1) * 16 + lrow) * 40 + quad * 8];
#pragma unroll
        for (int mi = 0; mi < 4; ++mi) {
            short8 a = *(const short8*)&lA[buf][(mi * 16 + lrow) * 40 + quad * 8];
            acc[mi][0] = MFMA(a, b0, acc[mi][0]);
            acc[mi][1] = MFMA(a, b1, acc[mi][1]);
        }
        if (ks < 35) storeChunk(buf ^ 1);
        __syncthreads();
    }

    if (mode == 0) {
        unsigned short* qn = qt + (size_t)n * PP * CH;
#pragma unroll
        for (int mi = 0; mi < 4; ++mi)
#pragma unroll
            for (int r = 0; r < 4; ++r) {
                int p = tile0 + mi * 16 + quad * 4 + r;
                if (p < PP)
#pragma unroll
                    for (int ni = 0; ni < 2; ++ni)
                        qn[(size_t)p * CH + (wave * 2 + ni) * 16 + lrow] = f2bf(acc[mi][ni][r]);
            }
    } else if (mode == 1) {
        unsigned short* kn = kt + (size_t)n * DD * CH;
#pragma unroll
        for (int mi = 0; mi < 4; ++mi)
#pragma unroll
            for (int r = 0; r < 4; ++r) {
                int d = tile0 + mi * 16 + quad * 4 + r;
                if (d < DD)
#pragma unroll
                    for (int ni = 0; ni < 2; ++ni)
                        kn[(size_t)d * CH + (wave * 2 + ni) * 16 + lrow] = f2bf(acc[mi][ni][r]);
            }
    } else {
        unsigned short* vn = vb + (size_t)n * CH * VP;
#pragma unroll
        for (int mi = 0; mi < 4; ++mi)
#pragma unroll
            for (int r = 0; r < 4; ++r) {
                int d = tile0 + mi * 16 + quad * 4 + r;
                if (d < DD)
#pragma unroll
                    for (int ni = 0; ni < 2; ++ni)
                        vn[(size_t)((wave * 2 + ni) * 16 + lrow) * VP + d] = f2bf(acc[mi][ni][r]);
            }
    }
}

// ---------------------------------------------------------------------------
// partial attention, LDS-staged (k_conv recipe), explicit loads (no lambdas).
// Block = 4 waves on a (64q x 128d) pair; wave w owns q-tile qg*4+w.
// S-phase: 4 c-chunks of 32; K-chunk [128d x 32c] staged double-buffered
// (pitch 40) while MFMAing the previous chunk. Split softmax (m,l per row).
// PV-phase: same loop staging V-chunks [128c x 32d]; lS reuse is separated
// from the last S read by two barriers. Tail q-tiles (>=81) compute on
// clamped rows, skip writes (barriers stay uniform). Grid (21, 10, 8).
// ---------------------------------------------------------------------------
__global__ __launch_bounds__(256)
void k_attn(const unsigned short* __restrict__ qt, const unsigned short* __restrict__ kt,
            const unsigned short* __restrict__ vb, _Float16* __restrict__ po,
            float* __restrict__ pm, float* __restrict__ pl)
{
    __shared__ unsigned short lS[2][128 * 40];    // 2 x 10240 B chunk staging
    __shared__ unsigned short lp[4][16 * 136];    // per-wave P transpose
    const int t = threadIdx.x;
    const int wave = t >> 6, lane = t & 63;
    const int quad = lane >> 4, lrow = lane & 15;
    const int qg = blockIdx.x;
    const int dt = blockIdx.y;
    const int n = blockIdx.z;
    const int qti = qg * 4 + wave;                // may be >= QT (tail)
    const int d0 = dt * 128;
    const unsigned short* qn = qt + (size_t)n * PP * CH;
    const unsigned short* kn = kt + (size_t)n * DD * CH;
    const unsigned short* vn = vb + (size_t)n * CH * VP;

    // staging roles: thread covers rows arow and arow+64, 8-short segment aseg8
    const int arow = t >> 2, aseg8 = (t & 3) * 8;
    int kr0 = d0 + arow;      if (kr0 >= DD) kr0 = DD - 1;
    int kr1 = d0 + arow + 64; if (kr1 >= DD) kr1 = DD - 1;
    const unsigned short* kp0 = kn + (size_t)kr0 * CH + aseg8;
    const unsigned short* kp1 = kn + (size_t)kr1 * CH + aseg8;
    const unsigned short* vp0 = vn + (size_t)arow * VP + d0 + aseg8;
    const unsigned short* vp1 = vn + (size_t)(arow + 64) * VP + d0 + aseg8;
    const int lo0 = arow * 40 + aseg8;
    const int lo1 = (arow + 64) * 40 + aseg8;

    // Q fragments held in registers for the whole kernel
    short8 qa[4];
    {
        int qrow = qti * 16 + lrow; if (qrow >= PP) qrow = PP - 1;
#pragma unroll
        for (int ks = 0; ks < 4; ++ks)
            qa[ks] = *(const short8*)&qn[(size_t)qrow * CH + ks * 32 + quad * 8];
    }

    // ---- S = Q.K^T, chunked over c, double-buffered ----
    f32x4 s[8] = {};
    uint4 r0 = *(const uint4*)kp0;
    uint4 r1 = *(const uint4*)kp1;
    *(uint4*)&lS[0][lo0] = r0;
    *(uint4*)&lS[0][lo1] = r1;
    __syncthreads();
#pragma unroll
    for (int ks = 0; ks < 4; ++ks) {
        const int buf = ks & 1;
        if (ks < 3) {
            r0 = *(const uint4*)(kp0 + (ks + 1) * 32);
            r1 = *(const uint4*)(kp1 + (ks + 1) * 32);
        }
#pragma unroll
        for (int ni = 0; ni < 8; ++ni) {
            short8 b = *(const short8*)&lS[buf][(ni * 16 + lrow) * 40 + quad * 8];
            s[ni] = MFMA(qa[ks], b, s[ni]);
        }
        if (ks < 3) {
            *(uint4*)&lS[buf ^ 1][lo0] = r0;
            *(uint4*)&lS[buf ^ 1][lo1] = r1;
        }
        __syncthreads();
    }

    // ---- tail mask + partial softmax (per wave) ----
#pragma unroll
    for (int ni = 0; ni < 8; ++ni)
        if (d0 + ni * 16 + lrow >= DD)
#pragma unroll
            for (int r = 0; r < 4; ++r) s[ni][r] = -1e30f;

    float mx[4] = {-1e30f, -1e30f, -1e30f, -1e30f};
#pragma unroll
    for (int ni = 0; ni < 8; ++ni)
#pragma unroll
        for (int r = 0; r < 4; ++r) mx[r] = fmaxf(mx[r], s[ni][r]);
#pragma unroll
    for (int off = 1; off < 16; off <<= 1)
#pragma unroll
        for (int r = 0; r < 4; ++r) mx[r] = fmaxf(mx[r], __shfl_xor(mx[r], off, 64));

    float rs[4] = {0.f, 0.f, 0.f, 0.f};
#pragma unroll
    for (int ni = 0; ni < 8; ++ni)
#pragma unroll
        for (int r = 0; r < 4; ++r) {
            float e = __expf(s[ni][r] - mx[r]);
            s[ni][r] = e;
            rs[r] += e;
        }
#pragma unroll
    for (int off = 1; off < 16; off <<= 1)
#pragma unroll
        for (int r = 0; r < 4; ++r) rs[r] += __shfl_xor(rs[r], off, 64);

    // P -> wave-private LDS (C-layout -> A-layout transpose)
#pragma unroll
    for (int ni = 0; ni < 8; ++ni)
#pragma unroll
        for (int r = 0; r < 4; ++r)
            lp[wave][(quad * 4 + r) * 136 + ni * 16 + lrow] = f2bf(s[ni][r]);

    // ---- O = P.V, chunked over d (lS reuse safe: two barriers since last read) ----
    f32x4 o[8] = {};
    r0 = *(const uint4*)vp0;
    r1 = *(const uint4*)vp1;
    *(uint4*)&lS[0][lo0] = r0;
    *(uint4*)&lS[0][lo1] = r1;
    __syncthreads();
#pragma unroll
    for (int ks = 0; ks < 4; ++ks) {
        const int buf = ks & 1;
        if (ks < 3) {
            r0 = *(const uint4*)(vp0 + (ks + 1) * 32);
            r1 = *(const uint4*)(vp1 + (ks + 1) * 32);
        }
        short8 pa = *(const short8*)&lp[wave][lrow * 136 + ks * 32 + quad * 8];
#pragma unroll
        for (int ni = 0; ni < 8; ++ni) {
            short8 b = *(const short8*)&lS[buf][(ni * 16 + lrow) * 40 + quad * 8];
            o[ni] = MFMA(pa, b, o[ni]);
        }
        if (ks < 3) {
            *(uint4*)&lS[buf ^ 1][lo0] = r0;
            *(uint4*)&lS[buf ^ 1][lo1] = r1;
        }
        __syncthreads();
    }

    if (qti < QT) {
        const int base = (n * QT + qti) * DT + dt;
        _Float16* pob = po + (size_t)base * 2048;
#pragma unroll
        for (int ni = 0; ni < 8; ++ni)
#pragma unroll
            for (int r = 0; r < 4; ++r)
                pob[(quad * 4 + r) * 128 + ni * 16 + lrow] = (_Float16)o[ni][r];
        if (lrow == 0)
#pragma unroll
            for (int r = 0; r < 4; ++r) {
                pm[base * 16 + quad * 4 + r] = mx[r];
                pl[base * 16 + quad * 4 + r] = rs[r];
            }
    }
}

// ---------------------------------------------------------------------------
// attention reduce — identical to round 11.
// ---------------------------------------------------------------------------
__global__ __launch_bounds__(256)
void k_ared(const _Float16* __restrict__ po, const float* __restrict__ pm,
            const float* __restrict__ pl, unsigned short* __restrict__ a0t)
{
    __shared__ float sm[160], ssc[160], smg[16], sli[16];
    const int qti = blockIdx.x;
    const int n = blockIdx.y;
    const int base = (n * QT + qti) * DT;
    const int t = threadIdx.x;
    if (t < 160) sm[t] = pm[base * 16 + t];
    __syncthreads();
    if (t < 16) {
        float mg = -1e30f;
#pragma unroll
        for (int dt = 0; dt < DT; ++dt) mg = fmaxf(mg, sm[dt * 16 + t]);
        float ls = 0.f;
#pragma unroll
        for (int dt = 0; dt < DT; ++dt) ls += __expf(sm[dt * 16 + t] - mg) * pl[base * 16 + dt * 16 + t];
        smg[t] = mg; sli[t] = 1.f / ls;
    }
    __syncthreads();
    if (t < 160) ssc[t] = __expf(sm[t] - smg[t & 15]);
    __syncthreads();

    unsigned short* an = a0t + (size_t)n * PP * CH;
#pragma unroll
    for (int k = 0; k < 8; ++k) {
        int idx = t + k * 256;
        int row = idx >> 7, c = idx & 127;
        float acc = 0.f;
#pragma unroll
        for (int dt = 0; dt < DT; ++dt)
            acc += ssc[dt * 16 + row] * (float)po[(size_t)(base + dt) * 2048 + idx];
        an[(size_t)(qti * 16 + row) * CH + c] = f2bf(acc * sli[row]);
    }
}

// ---------------------------------------------------------------------------
// fused h+out — identical to round 11.
// ---------------------------------------------------------------------------
__global__ __launch_bounds__(256)
void k_hout(const unsigned short* __restrict__ xt, const unsigned short* __restrict__ a0t,
            const unsigned short* __restrict__ whb, const float* __restrict__ hconst,
            const unsigned short* __restrict__ wob, const float* __restrict__ bo,
            float* __restrict__ out)
{
    __shared__ unsigned short lh[16 * 136];
    const int t = threadIdx.x;
    const int wave = t >> 6, lane = t & 63;
    const int quad = lane >> 4, lrow = lane & 15;
    const int p0 = blockIdx.x * 16;
    const int n = blockIdx.y;
    const unsigned short* x0 = xt + (size_t)n * PP * CH;
    const unsigned short* a0 = a0t + (size_t)n * PP * CH;

    f32x4 acc[2] = {};
#pragma unroll
    for (int ks = 0; ks < 8; ++ks) {
        int col = (ks & 3) * 32 + quad * 8;
        const unsigned short* src = (ks < 4) ? x0 : a0;
        short8 a = *(const short8*)&src[(size_t)(p0 + lrow) * CH + col];
#pragma unroll
        for (int j = 0; j < 2; ++j) {
            int ni = wave * 2 + j;
            short8 b = *(const short8*)&whb[(size_t)(ni * 16 + lrow) * 256 + ks * 32 + quad * 8];
            acc[j] = MFMA(a, b, acc[j]);
        }
    }
#pragma unroll
    for (int j = 0; j < 2; ++j) {
        int ni = wave * 2 + j;
        float hc = hconst[ni * 16 + lrow];
#pragma unroll
        for (int r = 0; r < 4; ++r)
            lh[(quad * 4 + r) * 136 + ni * 16 + lrow] = f2bf(fast_tanh(acc[j][r] + hc));
    }
    __syncthreads();

    f32x4 acc2[2] = {};
#pragma unroll
    for (int ks = 0; ks < 4; ++ks) {
        short8 a = *(const short8*)&lh[lrow * 136 + ks * 32 + quad * 8];
#pragma unroll
        for (int j = 0; j < 2; ++j) {
            int ni = wave * 2 + j;
            short8 b = *(const short8*)&wob[(size_t)(ni * 16 + lrow) * CH + ks * 32 + quad * 8];
            acc2[j] = MFMA(a, b, acc2[j]);
        }
    }
#pragma unroll
    for (int j = 0; j < 2; ++j) {
        int ni = wave * 2 + j;
        float bv = bo[ni * 16 + lrow];
#pragma unroll
        for (int r = 0; r < 4; ++r)
            out[((size_t)(n * CH + ni * 16 + lrow)) * PP + p0 + quad * 4 + r] = acc2[j][r] + bv;
    }
}

// ---------------------------------------------------------------------------
extern "C" void kernel_launch(void* const* d_in, const int* in_sizes, int n_in,
                              void* d_out, int out_size, void* d_ws, size_t ws_size,
                              hipStream_t stream)
{
    const float* inp  = (const float*)d_in[0];
    const float* c0   = (const float*)d_in[1];
    const float* w_x  = (const float*)d_in[2];
    const float* b_x  = (const float*)d_in[3];
    const float* w_qx = (const float*)d_in[4];
    const float* w_kx = (const float*)d_in[6];
    const float* w_vx = (const float*)d_in[8];
    const float* w_vc = (const float*)d_in[9];
    const float* w_h  = (const float*)d_in[14];
    const float* b_h  = (const float*)d_in[15];
    const float* w_o  = (const float*)d_in[16];
    const float* b_o  = (const float*)d_in[17];
    float* out = (float*)d_out;

    char* w = (char*)d_ws;
    unsigned short* xt   = (unsigned short*)(w);             // 2,654,208
    unsigned short* qt   = (unsigned short*)(w + 2654208);   // 2,654,208
    unsigned short* kt   = (unsigned short*)(w + 5308416);   // 2,367,488
    unsigned short* vb   = (unsigned short*)(w + 7675904);   // 2,621,440
    unsigned short* a0t  = (unsigned short*)(w + 10297344);  // 2,654,208
    unsigned short* wcat = (unsigned short*)(w + 12951552);  // 884,736
    unsigned short* wxb  = (unsigned short*)(w + 13836288);  // 32,768
    unsigned short* whb  = (unsigned short*)(w + 13869056);  // 65,536
    unsigned short* wob  = (unsigned short*)(w + 13934592);  // 32,768
    float* hconst        = (float*)(w + 13967360);           // 512
    float* pm            = (float*)(w + 13967872);           // 414,720
    float* pl            = (float*)(w + 14382592);           // 414,720
    _Float16* po         = (_Float16*)(w + 14797312);        // 26,542,080 -> 41.3 MB total

    hipLaunchKernelGGL(k_setup, dim3(577), dim3(256), 0, stream,
                       w_qx, w_kx, w_vx, w_h, w_o, w_x, c0, w_vc, b_h,
                       wcat, whb, wob, wxb, hconst);

    hipLaunchKernelGGL(k_proj, dim3(QT, 2, NN), dim3(64), 0, stream, inp, wxb, b_x, xt);

    hipLaunchKernelGGL(k_conv, dim3(21, 3, NN), dim3(256), 0, stream, xt, wcat, qt, kt, vb);

    hipLaunchKernelGGL(k_attn, dim3(21, DT, NN), dim3(256), 0, stream, qt, kt, vb, po, pm, pl);
    hipLaunchKernelGGL(k_ared, dim3(QT, NN), dim3(256), 0, stream, po, pm, pl, a0t);

    hipLaunchKernelGGL(k_hout, dim3(QT, NN), dim3(256), 0, stream,
                       xt, a0t, whb, hconst, wob, b_o, out);
}